// Round 13
// baseline (5008.876 us; speedup 1.0000x reference)
//
#include <hip/hip_runtime.h>
#include <hip/hip_bf16.h>
#include <math.h>

#define BATCH 128
#define QD 88
#define HDIM 512
#define ZDIM 1280
#define GDIM 2048
#define PROW 1536          // packed bytes per row (quad stride = 4*PROW = 6144)
#define QSTRIDE 6144
#define NPAST 10
#define NTRANS 29
#define NSTEPS (NPAST + NTRANS)
#define OUTD 95
#define POSE_ELEMS (BATCH * 30 * 91)

typedef float f32x4 __attribute__((ext_vector_type(4)));
typedef unsigned int u32x4 __attribute__((ext_vector_type(4)));

__device__ __forceinline__ float sig_(float x) { return 1.0f / (1.0f + expf(-x)); }
__device__ __forceinline__ void dot4_(const uint4 wv, const float4 zv, float& d) {
    const float4 f = *(const float4*)&wv;
    d = fmaf(f.x, zv.x, d); d = fmaf(f.y, zv.y, d);
    d = fmaf(f.z, zv.z, d); d = fmaf(f.w, zv.w, d);
}
__device__ __forceinline__ void fma4_(float4& acc, float x, const float4 w) {
    acc.x = fmaf(x, w.x, acc.x); acc.y = fmaf(x, w.y, acc.y);
    acc.z = fmaf(x, w.z, acc.z); acc.w = fmaf(x, w.w, acc.w);
}
__device__ __forceinline__ unsigned q12_(float w, float inv) {
    const unsigned u = __float2uint_rn(fmaf(w, inv, 2048.0f));
    return (u > 4095u) ? 4095u : u;
}
__device__ __forceinline__ void pack12_(const uint4 a, const uint4 b, float inv,
                                        unsigned& o0, unsigned& o1, unsigned& o2) {
    const unsigned u0 = q12_(__uint_as_float(a.x), inv), u1 = q12_(__uint_as_float(a.y), inv);
    const unsigned u2 = q12_(__uint_as_float(a.z), inv), u3 = q12_(__uint_as_float(a.w), inv);
    const unsigned u4 = q12_(__uint_as_float(b.x), inv), u5 = q12_(__uint_as_float(b.y), inv);
    const unsigned u6 = q12_(__uint_as_float(b.z), inv), u7 = q12_(__uint_as_float(b.w), inv);
    o0 = u0 | (u1 << 12) | (u2 << 24);
    o1 = (u2 >> 8) | (u3 << 4) | (u4 << 16) | (u5 << 28);
    o2 = (u5 >> 4) | (u6 << 8) | (u7 << 20);
}
// signed dot of an 8-weight packet with two float4 z fragments (field - 2048)
__device__ __forceinline__ float dot12_(unsigned d0, unsigned d1, unsigned d2,
                                        const float4 za, const float4 zb) {
    float acc = 0.f;
    acc = fmaf((float)((int)(d0 & 0xFFFu) - 2048), za.x, acc);
    acc = fmaf((float)((int)((d0 >> 12) & 0xFFFu) - 2048), za.y, acc);
    acc = fmaf((float)((int)((d0 >> 24) | ((d1 & 0xFu) << 8)) - 2048), za.z, acc);
    acc = fmaf((float)((int)((d1 >> 4) & 0xFFFu) - 2048), za.w, acc);
    acc = fmaf((float)((int)((d1 >> 16) & 0xFFFu) - 2048), zb.x, acc);
    acc = fmaf((float)((int)((d1 >> 28) | ((d2 & 0xFFu) << 4)) - 2048), zb.y, acc);
    acc = fmaf((float)((int)((d2 >> 8) & 0xFFFu) - 2048), zb.z, acc);
    acc = fmaf((float)((int)(d2 >> 20) - 2048), zb.w, acc);
    return acc;
}
__device__ __forceinline__ float wredmax_(float m) {
    #pragma unroll
    for (int s = 32; s >= 1; s >>= 1) m = fmaxf(m, __shfl_xor(m, s, 64));
    return m;
}
__device__ __forceinline__ float amax4_(const uint4 a, float m) {
    m = fmaxf(m, fabsf(__uint_as_float(a.x))); m = fmaxf(m, fabsf(__uint_as_float(a.y)));
    m = fmaxf(m, fabsf(__uint_as_float(a.z))); m = fmaxf(m, fabsf(__uint_as_float(a.w)));
    return m;
}

// ---- step-0 GEMV over fp32 weights, fused with int12 quantization + static fold ----
__global__ void __launch_bounds__(256)
matvec0_conv(const float* __restrict__ W, const float* __restrict__ z_ws,
             const float* __restrict__ pred_bias, unsigned char* __restrict__ Wp,
             float* __restrict__ scale_ws, float* __restrict__ g_ws, float* __restrict__ g0_ws)
{
    const int b = blockIdx.x >> 5, chunk = blockIdx.x & 31;
    const int wave = threadIdx.x >> 6, lane = threadIdx.x & 63;
    const int row0 = chunk * 64 + wave * 16;
    const float* zb = z_ws + b * ZDIM;
    const float biasv = (lane < 16) ? pred_bias[b * GDIM + row0 + lane] : 0.f;
    const int l4 = lane * 4;
    const float4 z0 = *(const float4*)(zb + l4);
    const float4 z1 = *(const float4*)(zb + 256 + l4);
    const float4 zh = *(const float4*)(zb + 512 + l4);
    const float4 z3 = *(const float4*)(zb + 768 + l4);
    const float4 z4 = *(const float4*)(zb + 1024 + l4);
    const char* wb = (const char*)W + (size_t)b * GDIM * ZDIM * 4;
    char* dstB = (char*)Wp + (size_t)b * GDIM * PROW;

    #define ISSUE(p, B) { const char* a_ = wb + (size_t)(row0 + 2 * (p)) * (ZDIM * 4) + lane * 16; \
        _Pragma("unroll") for (int i = 0; i < 10; ++i) B[i] = *(const uint4*)(a_ + i * 1024); }

    uint4 bufa[10], bufb[10];
    unsigned sst[6], hst[6];
    ISSUE(0, bufa);
    #pragma unroll
    for (int p = 0; p < 8; ++p) {
        uint4* cur = (p & 1) ? bufb : bufa;
        uint4* nxt = (p & 1) ? bufa : bufb;
        if (p < 7) ISSUE(p + 1, nxt);
        float dynA = 0.f, dynB = 0.f, statA = 0.f, statB = 0.f;
        dot4_(cur[0], z0, dynA); dot4_(cur[1], z1, dynA);
        dot4_(cur[2], zh, statA);
        dot4_(cur[3], z3, dynA); dot4_(cur[4], z4, dynA);
        dot4_(cur[5], z0, dynB); dot4_(cur[6], z1, dynB);
        dot4_(cur[7], zh, statB);
        dot4_(cur[8], z3, dynB); dot4_(cur[9], z4, dynB);
        float m0 = 0.f, m1 = 0.f;
        m0 = amax4_(cur[0], m0); m0 = amax4_(cur[1], m0);
        m0 = amax4_(cur[3], m0); m0 = amax4_(cur[4], m0);
        m1 = amax4_(cur[5], m1); m1 = amax4_(cur[6], m1);
        m1 = amax4_(cur[8], m1); m1 = amax4_(cur[9], m1);
        m0 = wredmax_(m0); m1 = wredmax_(m1);
        const float s0 = m0 * (1.f / 2047.f), s1 = m1 * (1.f / 2047.f);
        const float inv0 = (m0 > 0.f) ? 2047.f / m0 : 0.f;
        const float inv1 = (m1 > 0.f) ? 2047.f / m1 : 0.f;
        unsigned s0a, s0b, s0c, h0a, h0b, h0c, s1a, s1b, s1c, h1a, h1b, h1c;
        pack12_(cur[0], cur[1], inv0, s0a, s0b, s0c);
        pack12_(cur[3], cur[4], inv0, h0a, h0b, h0c);
        pack12_(cur[5], cur[6], inv1, s1a, s1b, s1c);
        pack12_(cur[8], cur[9], inv1, h1a, h1b, h1c);
        if ((p & 1) == 0) {
            sst[0] = s0a; sst[1] = s0b; sst[2] = s0c; sst[3] = s1a; sst[4] = s1b; sst[5] = s1c;
            hst[0] = h0a; hst[1] = h0b; hst[2] = h0c; hst[3] = h1a; hst[4] = h1b; hst[5] = h1c;
        } else {
            char* base = dstB + (size_t)((row0 + 2 * p) >> 2) * QSTRIDE + lane * 16;
            u32x4 v;
            v.x = sst[0]; v.y = sst[1]; v.z = sst[2]; v.w = sst[3];
            __builtin_nontemporal_store(v, (u32x4*)(base));
            v.x = sst[4]; v.y = sst[5]; v.z = s0a; v.w = s0b;
            __builtin_nontemporal_store(v, (u32x4*)(base + 1024));
            v.x = s0c; v.y = s1a; v.z = s1b; v.w = s1c;
            __builtin_nontemporal_store(v, (u32x4*)(base + 2048));
            v.x = hst[0]; v.y = hst[1]; v.z = hst[2]; v.w = hst[3];
            __builtin_nontemporal_store(v, (u32x4*)(base + 3072));
            v.x = hst[4]; v.y = hst[5]; v.z = h0a; v.w = h0b;
            __builtin_nontemporal_store(v, (u32x4*)(base + 4096));
            v.x = h0c; v.y = h1a; v.z = h1b; v.w = h1c;
            __builtin_nontemporal_store(v, (u32x4*)(base + 5120));
        }
        if (lane == 0) { scale_ws[b * GDIM + row0 + 2 * p] = s0;
                         scale_ws[b * GDIM + row0 + 2 * p + 1] = s1; }
        float sd0 = dynA + __shfl_xor(dynA, 32);
        float sd1 = dynB + __shfl_xor(dynB, 32);
        float ud = (lane < 32) ? sd0 : sd1;
        float ss0 = statA + __shfl_xor(statA, 32);
        float ss1 = statB + __shfl_xor(statB, 32);
        float us = (lane < 32) ? ss0 : ss1;
        #pragma unroll
        for (int m = 16; m >= 1; m >>= 1) { ud += __shfl_xor(ud, m); us += __shfl_xor(us, m); }
        const float badd = __shfl(biasv, 2 * p + ((lane >= 32) ? 1 : 0), 64);
        if (lane == 0 || lane == 32) {
            const int r = row0 + 2 * p + ((lane >= 32) ? 1 : 0);
            g0_ws[b * GDIM + r] = us + badd;
            g_ws[b * GDIM + r]  = ud + us + badd;
        }
    }
    #undef ISSUE
}

// helper: reduce a row pair (rA,rB) across the wave, add base+scale, write 2 rows
__device__ __forceinline__ void redwrite_(float rA, float rB, int lane,
                                          float g0v, float scv, int idx0,
                                          float* __restrict__ dst, int drow0) {
    const float sA = rA + __shfl_xor(rA, 32);
    const float sB = rB + __shfl_xor(rB, 32);
    float u = (lane < 32) ? sA : sB;
    #pragma unroll
    for (int m = 16; m >= 1; m >>= 1) u += __shfl_xor(u, m);
    const int hilo = (lane >= 32) ? 1 : 0;
    const float badd = __shfl(g0v, idx0 + hilo, 64);
    const float srow = __shfl(scv, idx0 + hilo, 64);
    const float val = badd + srow * u;
    if (lane == 0)       dst[drow0] = val;
    else if (lane == 32) dst[drow0 + 1] = val;
}

// ---- E-pass: E[s][b][row] = g0 + s_row*(W_state . enc[s])  (state blocks only) ----
__global__ void __launch_bounds__(256)
epass(const unsigned char* __restrict__ Wp, const float* __restrict__ enc9,
      const float* __restrict__ scale_ws, const float* __restrict__ g0_ws,
      float* __restrict__ E_ws)
{
    const int b = blockIdx.x >> 5, chunk = blockIdx.x & 31;
    const int wave = threadIdx.x >> 6, lane = threadIdx.x & 63;
    const int row0 = chunk * 64 + wave * 16;
    const int q0 = row0 >> 2;
    const int l4 = lane * 4;
    float4 eA[9], eB[9];
    #pragma unroll
    for (int s = 0; s < 9; ++s) {
        const float* eb = enc9 + ((size_t)s * BATCH + b) * 512;
        eA[s] = *(const float4*)(eb + l4);
        eB[s] = *(const float4*)(eb + 256 + l4);
    }
    const float g0v = (lane < 16) ? g0_ws[b * GDIM + row0 + lane] : 0.f;
    const float scv = (lane < 16) ? scale_ws[b * GDIM + row0 + lane] : 0.f;
    const char* wb = (const char*)Wp + (size_t)b * GDIM * PROW;

    #define ISSUE(qq, B) { const char* a_ = wb + (size_t)(q0 + (qq)) * QSTRIDE + lane * 16; \
        B[0] = __builtin_nontemporal_load((const u32x4*)(a_)); \
        B[1] = __builtin_nontemporal_load((const u32x4*)(a_ + 1024)); \
        B[2] = __builtin_nontemporal_load((const u32x4*)(a_ + 2048)); }

    u32x4 bufa[3], bufb[3];
    ISSUE(0, bufa);
    #pragma unroll
    for (int qq = 0; qq < 4; ++qq) {
        u32x4* cur = (qq & 1) ? bufb : bufa;
        u32x4* nxt = (qq & 1) ? bufa : bufb;
        if (qq < 3) ISSUE(qq + 1, nxt);
        #pragma unroll
        for (int s = 0; s < 9; ++s) {
            const float r0 = dot12_(cur[0].x, cur[0].y, cur[0].z, eA[s], eB[s]);
            const float r1 = dot12_(cur[0].w, cur[1].x, cur[1].y, eA[s], eB[s]);
            const float r2 = dot12_(cur[1].z, cur[1].w, cur[2].x, eA[s], eB[s]);
            const float r3 = dot12_(cur[2].y, cur[2].z, cur[2].w, eA[s], eB[s]);
            float* dst = E_ws + ((size_t)s * BATCH + b) * GDIM;
            redwrite_(r0, r1, lane, g0v, scv, 4 * qq,     dst, row0 + 4 * qq);
            redwrite_(r2, r3, lane, g0v, scv, 4 * qq + 2, dst, row0 + 4 * qq + 2);
        }
    }
    #undef ISSUE
}

// ---- past-step GEMV (s=1..9): gates = E[s] + s_row*(W_h . h)  (h blocks, L3) ----
__global__ void __launch_bounds__(256)
matvecH(const unsigned char* __restrict__ Wp, const float* __restrict__ z_ws,
        const float* __restrict__ scale_ws, const float* __restrict__ Es,
        float* __restrict__ g_ws)
{
    const int b = blockIdx.x >> 5, chunk = blockIdx.x & 31;
    const int wave = threadIdx.x >> 6, lane = threadIdx.x & 63;
    const int row0 = chunk * 64 + wave * 16;
    const int q0 = row0 >> 2;
    const float* zb = z_ws + b * ZDIM;
    const int l4 = lane * 4;
    const float4 z3 = *(const float4*)(zb + 768 + l4);
    const float4 z4 = *(const float4*)(zb + 1024 + l4);
    const float Ev  = (lane < 16) ? Es[b * GDIM + row0 + lane] : 0.f;
    const float scv = (lane < 16) ? scale_ws[b * GDIM + row0 + lane] : 0.f;
    const char* wb = (const char*)Wp + (size_t)b * GDIM * PROW;

    #define ISSUE(qq, B) { const char* a_ = wb + (size_t)(q0 + (qq)) * QSTRIDE + 3072 + lane * 16; \
        B[0] = *(const u32x4*)(a_); \
        B[1] = *(const u32x4*)(a_ + 1024); \
        B[2] = *(const u32x4*)(a_ + 2048); }

    u32x4 buf0[3], buf1[3], buf2[3];
    ISSUE(0, buf0);
    ISSUE(1, buf1);
    #pragma unroll
    for (int qq = 0; qq < 4; ++qq) {
        u32x4* cur = (qq % 3 == 0) ? buf0 : (qq % 3 == 1) ? buf1 : buf2;
        u32x4* nxt = ((qq + 2) % 3 == 0) ? buf0 : ((qq + 2) % 3 == 1) ? buf1 : buf2;
        if (qq < 2) ISSUE(qq + 2, nxt);
        const float r0 = dot12_(cur[0].x, cur[0].y, cur[0].z, z3, z4);
        const float r1 = dot12_(cur[0].w, cur[1].x, cur[1].y, z3, z4);
        const float r2 = dot12_(cur[1].z, cur[1].w, cur[2].x, z3, z4);
        const float r3 = dot12_(cur[2].y, cur[2].z, cur[2].w, z3, z4);
        float* dst = g_ws + b * GDIM;
        redwrite_(r0, r1, lane, Ev, scv, 4 * qq,     dst, row0 + 4 * qq);
        redwrite_(r2, r3, lane, Ev, scv, 4 * qq + 2, dst, row0 + 4 * qq + 2);
    }
    #undef ISSUE
}

// ---- transition-step GEMV over int12 quad layout: PLAIN loads (let L3 retain) ----
__global__ void __launch_bounds__(256)
matvec12(const unsigned char* __restrict__ Wp, const float* __restrict__ z_ws,
         const float* __restrict__ scale_ws, const float* __restrict__ g0_ws,
         float* __restrict__ g_ws)
{
    const int b = blockIdx.x >> 5, chunk = blockIdx.x & 31;
    const int wave = threadIdx.x >> 6, lane = threadIdx.x & 63;
    const int row0 = chunk * 64 + wave * 16;
    const int q0 = row0 >> 2;
    const float* zb = z_ws + b * ZDIM;
    const int l4 = lane * 4;
    const float4 z0 = *(const float4*)(zb + l4);
    const float4 z1 = *(const float4*)(zb + 256 + l4);
    const float4 z3 = *(const float4*)(zb + 768 + l4);
    const float4 z4 = *(const float4*)(zb + 1024 + l4);
    const float g0v = (lane < 16) ? g0_ws[b * GDIM + row0 + lane] : 0.f;
    const float scv = (lane < 16) ? scale_ws[b * GDIM + row0 + lane] : 0.f;
    const char* wb = (const char*)Wp + (size_t)b * GDIM * PROW;

    #define ISSUE(qq, B) { const char* a_ = wb + (size_t)(q0 + (qq)) * QSTRIDE + lane * 16; \
        B[0] = *(const u32x4*)(a_); \
        B[1] = *(const u32x4*)(a_ + 1024); \
        B[2] = *(const u32x4*)(a_ + 2048); \
        B[3] = *(const u32x4*)(a_ + 3072); \
        B[4] = *(const u32x4*)(a_ + 4096); \
        B[5] = *(const u32x4*)(a_ + 5120); }

    u32x4 buf0[6], buf1[6], buf2[6];
    ISSUE(0, buf0);
    ISSUE(1, buf1);
    #pragma unroll
    for (int qq = 0; qq < 4; ++qq) {
        u32x4* cur = (qq % 3 == 0) ? buf0 : (qq % 3 == 1) ? buf1 : buf2;
        u32x4* nxt = ((qq + 2) % 3 == 0) ? buf0 : ((qq + 2) % 3 == 1) ? buf1 : buf2;
        if (qq < 2) ISSUE(qq + 2, nxt);
        const float r0 = dot12_(cur[0].x, cur[0].y, cur[0].z, z0, z1)
                       + dot12_(cur[3].x, cur[3].y, cur[3].z, z3, z4);
        const float r1 = dot12_(cur[0].w, cur[1].x, cur[1].y, z0, z1)
                       + dot12_(cur[3].w, cur[4].x, cur[4].y, z3, z4);
        const float r2 = dot12_(cur[1].z, cur[1].w, cur[2].x, z0, z1)
                       + dot12_(cur[4].z, cur[4].w, cur[5].x, z3, z4);
        const float r3 = dot12_(cur[2].y, cur[2].z, cur[2].w, z0, z1)
                       + dot12_(cur[5].y, cur[5].z, cur[5].w, z3, z4);
        float* dst = g_ws + b * GDIM;
        redwrite_(r0, r1, lane, g0v, scv, 4 * qq,     dst, row0 + 4 * qq);
        redwrite_(r2, r3, lane, g0v, scv, 4 * qq + 2, dst, row0 + 4 * qq + 2);
    }
    #undef ISSUE
}

// ---- LSTM-only step for past steps 0..8 (decoder provably dead there) ----
__global__ void __launch_bounds__(512)
lstmk(const float* __restrict__ g_ws, float* __restrict__ z_ws, float* __restrict__ c_ws)
{
    const int b = blockIdx.x, t = threadIdx.x;
    const float* g = g_ws + b * GDIM;
    const float ig = g[t], fg = g[512 + t], gg = g[1024 + t], og = g[1536 + t];
    const float c2 = sig_(fg) * c_ws[b * HDIM + t] + sig_(ig) * tanhf(gg);
    c_ws[b * HDIM + t] = c2;
    z_ws[b * ZDIM + 768 + t] = sig_(og) * tanhf(c2);
}

// ---------------- init: state=0, h_target, step-0 encoders, glob presum ----------------
__global__ void __launch_bounds__(512)
initk(const float* __restrict__ past_root_vel, const float* __restrict__ past_quats,
      const float* __restrict__ past_root_offset, const float* __restrict__ past_quat_offset,
      const float* __restrict__ past_contacts, const float* __restrict__ target_quats,
      const float* __restrict__ init_root_pos,
      const float* __restrict__ se_w1, const float* __restrict__ se_b1,
      const float* __restrict__ se_w2, const float* __restrict__ se_b2,
      const float* __restrict__ oe_w1, const float* __restrict__ oe_b1,
      const float* __restrict__ oe_w2, const float* __restrict__ oe_b2,
      const float* __restrict__ te_w1, const float* __restrict__ te_b1,
      const float* __restrict__ te_w2, const float* __restrict__ te_b2,
      float* __restrict__ z_ws, float* __restrict__ c_ws, float* __restrict__ car_ws)
{
    const int b = blockIdx.x, t = threadIdx.x;
    __shared__ float tq[QD], bufA[512], bufB[512], sv[95], ov[91];

    if (t < 192) {
        float v = 0.f;
        if (t < 3) {
            v = init_root_pos[b * 3 + t];
            // glob after past steps 0..8 (lstmk path skips the per-step accumulation)
            for (int s = 0; s < NPAST - 1; ++s) v += past_root_vel[(b * NPAST + s) * 3 + t];
        }
        car_ws[b * 192 + t] = v;
    }
    c_ws[b * HDIM + t] = 0.f;
    z_ws[b * ZDIM + 768 + t] = 0.f;
    if (t < QD) tq[t] = target_quats[b * QD + t];
    if (t < 4)  sv[t] = past_contacts[b * NPAST * 4 + t];
    if (t < QD) { sv[4 + t] = past_quats[b * NPAST * QD + t];
                  ov[3 + t] = past_quat_offset[b * NPAST * QD + t]; }
    if (t < 3)  { sv[92 + t] = past_root_vel[b * NPAST * 3 + t];
                  ov[t]      = past_root_offset[b * NPAST * 3 + t]; }
    __syncthreads();
    {
        float a = te_b1[t];
        #pragma unroll 8
        for (int i = 0; i < QD; ++i) a = fmaf(tq[i], te_w1[i * 512 + t], a);
        bufA[t] = fmaxf(a, 0.f);
    }
    __syncthreads();
    if (t < 256) {
        float a = te_b2[t];
        #pragma unroll 8
        for (int i = 0; i < 512; ++i) a = fmaf(bufA[i], te_w2[i * 256 + t], a);
        z_ws[b * ZDIM + 512 + t] = fmaxf(a, 0.f);
    }
    __syncthreads();
    {
        float aS = se_b1[t], aO = oe_b1[t];
        #pragma unroll 8
        for (int i = 0; i < 91; ++i) { aS = fmaf(sv[i], se_w1[i * 512 + t], aS);
                                       aO = fmaf(ov[i], oe_w1[i * 512 + t], aO); }
        #pragma unroll
        for (int i = 91; i < 95; ++i) aS = fmaf(sv[i], se_w1[i * 512 + t], aS);
        bufA[t] = fmaxf(aS, 0.f);
        bufB[t] = fmaxf(aO, 0.f);
    }
    __syncthreads();
    if (t < 256) {
        float a = se_b2[t];
        #pragma unroll 8
        for (int i = 0; i < 512; ++i) a = fmaf(bufA[i], se_w2[i * 256 + t], a);
        z_ws[b * ZDIM + t] = fmaxf(a, 0.f);
    } else {
        const int j = t - 256;
        float a = oe_b2[j];
        #pragma unroll 8
        for (int i = 0; i < 512; ++i) a = fmaf(bufB[i], oe_w2[i * 256 + j], a);
        z_ws[b * ZDIM + 256 + j] = fmaxf(a, 0.f);
    }
}

// ---- batch-encode past steps 1..9 -> enc9[(s-1)*BATCH + b][512] ----
__global__ void __launch_bounds__(512)
enc_past(const float* __restrict__ past_root_vel, const float* __restrict__ past_quats,
         const float* __restrict__ past_root_offset, const float* __restrict__ past_quat_offset,
         const float* __restrict__ past_contacts,
         const float* __restrict__ se_w1, const float* __restrict__ se_b1,
         const float* __restrict__ se_w2, const float* __restrict__ se_b2,
         const float* __restrict__ oe_w1, const float* __restrict__ oe_b1,
         const float* __restrict__ oe_w2, const float* __restrict__ oe_b2,
         float* __restrict__ enc9)
{
    const int b = blockIdx.x, t = threadIdx.x;
    const int s = blockIdx.y + 1;
    __shared__ float bufA[512], bufB[512], sv[95], ov[91];

    if (t < 4)  sv[t] = past_contacts[(b * NPAST + s) * 4 + t];
    if (t < QD) { sv[4 + t] = past_quats[(b * NPAST + s) * QD + t];
                  ov[3 + t] = past_quat_offset[(b * NPAST + s) * QD + t]; }
    if (t < 3)  { sv[92 + t] = past_root_vel[(b * NPAST + s) * 3 + t];
                  ov[t]      = past_root_offset[(b * NPAST + s) * 3 + t]; }
    __syncthreads();
    {
        float aS = se_b1[t], aO = oe_b1[t];
        #pragma unroll 8
        for (int i = 0; i < 91; ++i) { aS = fmaf(sv[i], se_w1[i * 512 + t], aS);
                                       aO = fmaf(ov[i], oe_w1[i * 512 + t], aO); }
        #pragma unroll
        for (int i = 91; i < 95; ++i) aS = fmaf(sv[i], se_w1[i * 512 + t], aS);
        bufA[t] = fmaxf(aS, 0.f);
        bufB[t] = fmaxf(aO, 0.f);
    }
    __syncthreads();
    float* dst = enc9 + ((size_t)(s - 1) * BATCH + b) * 512;
    if (t < 256) {
        float a = se_b2[t];
        #pragma unroll 8
        for (int i = 0; i < 512; ++i) a = fmaf(bufA[i], se_w2[i * 256 + t], a);
        dst[t] = fmaxf(a, 0.f);
    } else {
        const int j = t - 256;
        float a = oe_b2[j];
        #pragma unroll 8
        for (int i = 0; i < 512; ++i) a = fmaf(bufB[i], oe_w2[i * 256 + j], a);
        dst[256 + j] = fmaxf(a, 0.f);
    }
}

// ---------------- per-step: LSTM + decoder + state update + next encoders ----------------
__global__ void __launch_bounds__(512)
stepk(const float* __restrict__ past_root_vel, const float* __restrict__ past_quats,
      const float* __restrict__ past_root_offset, const float* __restrict__ past_quat_offset,
      const float* __restrict__ past_contacts, const float* __restrict__ target_root_pos,
      const float* __restrict__ target_quats,
      const float* __restrict__ se_w1, const float* __restrict__ se_b1,
      const float* __restrict__ se_w2, const float* __restrict__ se_b2,
      const float* __restrict__ oe_w1, const float* __restrict__ oe_b1,
      const float* __restrict__ oe_w2, const float* __restrict__ oe_b2,
      const float* __restrict__ de_w1, const float* __restrict__ de_b1,
      const float* __restrict__ de_w2, const float* __restrict__ de_b2,
      const float* __restrict__ de_w3, const float* __restrict__ de_b3,
      float* __restrict__ out, float* __restrict__ z_ws, const float* __restrict__ g_ws,
      float* __restrict__ c_ws, float* __restrict__ car_ws, int s, int skip_enc)
{
    const int b = blockIdx.x, t = threadIdx.x;
    __shared__ float4 part4[512];
    __shared__ __align__(16) float h2s[HDIM], bufA[512], bufB[512], d2[256];
    __shared__ float outv[OUTD], nq[QD], sv[95], ov[91], carryL[192], tq[QD], trp[3];
    __shared__ float rvn[3], globn[3], contn[4];

    if (t < 192) carryL[t] = car_ws[b * 192 + t];
    if (t < QD) tq[t] = target_quats[b * QD + t];
    if (t < 3)  trp[t] = target_root_pos[b * 3 + t];

    {
        const float* g = g_ws + b * GDIM;
        const float ig = g[t], fg = g[512 + t], gg = g[1024 + t], og = g[1536 + t];
        const float c2 = sig_(fg) * c_ws[b * HDIM + t] + sig_(ig) * tanhf(gg);
        c_ws[b * HDIM + t] = c2;
        const float h2 = sig_(og) * tanhf(c2);
        h2s[t] = h2;
        z_ws[b * ZDIM + 768 + t] = h2;
    }
    __syncthreads();
    {
        const int c = t & 127, s4 = t >> 7;
        float4 acc = {0.f, 0.f, 0.f, 0.f};
        const float* w = de_w1 + (size_t)(s4 * 128) * 512 + 4 * c;
        #pragma unroll 8
        for (int k = 0; k < 128; ++k)
            fma4_(acc, h2s[s4 * 128 + k], *(const float4*)(w + (size_t)k * 512));
        part4[t] = acc;
    }
    __syncthreads();
    if (t < 128) {
        float4 v = part4[t];
        #pragma unroll
        for (int s4 = 1; s4 < 4; ++s4) { const float4 p = part4[s4 * 128 + t];
            v.x += p.x; v.y += p.y; v.z += p.z; v.w += p.w; }
        const float4 bb = *(const float4*)(de_b1 + 4 * t);
        float4 r; r.x = fmaxf(v.x + bb.x, 0.f); r.y = fmaxf(v.y + bb.y, 0.f);
        r.z = fmaxf(v.z + bb.z, 0.f); r.w = fmaxf(v.w + bb.w, 0.f);
        *(float4*)&bufA[4 * t] = r;
    }
    __syncthreads();
    {
        const int c = t & 63, s8 = t >> 6;
        float4 acc = {0.f, 0.f, 0.f, 0.f};
        const float* w = de_w2 + (size_t)(s8 * 64) * 256 + 4 * c;
        #pragma unroll 8
        for (int k = 0; k < 64; ++k)
            fma4_(acc, bufA[s8 * 64 + k], *(const float4*)(w + (size_t)k * 256));
        part4[t] = acc;
    }
    __syncthreads();
    if (t < 64) {
        float4 v = part4[t];
        #pragma unroll
        for (int s8 = 1; s8 < 8; ++s8) { const float4 p = part4[s8 * 64 + t];
            v.x += p.x; v.y += p.y; v.z += p.z; v.w += p.w; }
        const float4 bb = *(const float4*)(de_b2 + 4 * t);
        float4 r; r.x = fmaxf(v.x + bb.x, 0.f); r.y = fmaxf(v.y + bb.y, 0.f);
        r.z = fmaxf(v.z + bb.z, 0.f); r.w = fmaxf(v.w + bb.w, 0.f);
        *(float4*)&d2[4 * t] = r;
    }
    __syncthreads();
    if (t < OUTD) {
        float acc = de_b3[t];
        #pragma unroll 16
        for (int i = 0; i < 256; ++i) acc = fmaf(d2[i], de_w3[i * OUTD + t], acc);
        outv[t] = acc;
    }
    __syncthreads();

    const bool pastS = (s < NPAST);
    if (t < QD) {
        const float qin = pastS ? past_quats[(b * NPAST + s) * QD + t] : carryL[10 + t];
        nq[t] = outv[t] + qin;
    }
    __syncthreads();
    if (t < 22) {
        const float a = nq[4 * t], b2 = nq[4 * t + 1], c3 = nq[4 * t + 2], d4 = nq[4 * t + 3];
        const float inv = 1.f / fmaxf(sqrtf(a * a + b2 * b2 + c3 * c3 + d4 * d4), 1e-12f);
        nq[4 * t] = a * inv; nq[4 * t + 1] = b2 * inv; nq[4 * t + 2] = c3 * inv; nq[4 * t + 3] = d4 * inv;
    }
    if (t < 3) {
        const float rin = pastS ? past_root_vel[(b * NPAST + s) * 3 + t] : carryL[3 + t];
        const float nrv = outv[88 + t] + rin;
        const float g = carryL[t] + (pastS ? rin : nrv);
        rvn[t] = nrv; globn[t] = g;
    }
    if (t < 4) contn[t] = sig_(outv[91 + t]);
    __syncthreads();

    if (t < 3) { car_ws[b * 192 + t] = globn[t]; car_ws[b * 192 + 3 + t] = rvn[t];
                 car_ws[b * 192 + 186 + t] = globn[t] - trp[t]; }
    if (t < 4) car_ws[b * 192 + 6 + t] = contn[t];
    if (t < QD) { car_ws[b * 192 + 10 + t] = nq[t]; car_ws[b * 192 + 98 + t] = nq[t] - tq[t]; }
    if (s == NPAST - 1) {
        const size_t pb = (size_t)b * 30 * 91;
        if (t < 3)  out[pb + t] = rvn[t];
        if (t < QD) out[pb + 3 + t] = nq[t];
        if (t < 4)  out[POSE_ELEMS + (size_t)b * 30 * 4 + t] = contn[t];
    } else if (!pastS) {
        const int k = s - NPAST + 1;
        const size_t pb = ((size_t)b * 30 + k) * 91;
        if (t < 3)  out[pb + t] = globn[t];
        if (t < QD) out[pb + 3 + t] = nq[t];
        if (t < 4)  out[POSE_ELEMS + ((size_t)b * 30 + k) * 4 + t] = contn[t];
    }
    if (s == NSTEPS - 1) return;
    if (skip_enc) return;

    const int nx = s + 1;
    if (nx < NPAST) {
        if (t < 4)  sv[t] = past_contacts[(b * NPAST + nx) * 4 + t];
        if (t < QD) { sv[4 + t] = past_quats[(b * NPAST + nx) * QD + t];
                      ov[3 + t] = past_quat_offset[(b * NPAST + nx) * QD + t]; }
        if (t < 3)  { sv[92 + t] = past_root_vel[(b * NPAST + nx) * 3 + t];
                      ov[t]      = past_root_offset[(b * NPAST + nx) * 3 + t]; }
    } else {
        if (t < 4)  sv[t] = contn[t];
        if (t < QD) { sv[4 + t] = nq[t]; ov[3 + t] = nq[t] - tq[t]; }
        if (t < 3)  { sv[92 + t] = rvn[t]; ov[t] = globn[t] - trp[t]; }
    }
    __syncthreads();
    {
        const int tt = t & 255, enc = t >> 8;
        const int c = tt & 127, sl = tt >> 7;
        const float* inp = enc ? ov : sv;
        const float* w1  = enc ? oe_w1 : se_w1;
        const int nin  = enc ? 91 : 95;
        const int half = enc ? 46 : 48;
        const int i0 = sl * half;
        const int iend = (i0 + half < nin) ? (i0 + half) : nin;
        float4 acc = {0.f, 0.f, 0.f, 0.f};
        #pragma unroll 8
        for (int k = 0; k < 48; ++k) {
            const int i = i0 + k;
            if (i < iend) fma4_(acc, inp[i], *(const float4*)(w1 + (size_t)i * 512 + 4 * c));
        }
        part4[enc * 256 + tt] = acc;
    }
    __syncthreads();
    if (t < 128) {
        const float4 a = part4[t], b2 = part4[128 + t];
        const float4 bb = *(const float4*)(se_b1 + 4 * t);
        float4 r; r.x = fmaxf(a.x + b2.x + bb.x, 0.f); r.y = fmaxf(a.y + b2.y + bb.y, 0.f);
        r.z = fmaxf(a.z + b2.z + bb.z, 0.f); r.w = fmaxf(a.w + b2.w + bb.w, 0.f);
        *(float4*)&bufA[4 * t] = r;
    } else if (t < 256) {
        const int c = t - 128;
        const float4 a = part4[256 + c], b2 = part4[384 + c];
        const float4 bb = *(const float4*)(oe_b1 + 4 * c);
        float4 r; r.x = fmaxf(a.x + b2.x + bb.x, 0.f); r.y = fmaxf(a.y + b2.y + bb.y, 0.f);
        r.z = fmaxf(a.z + b2.z + bb.z, 0.f); r.w = fmaxf(a.w + b2.w + bb.w, 0.f);
        *(float4*)&bufB[4 * c] = r;
    }
    __syncthreads();
    {
        const int tt = t & 255, enc = t >> 8;
        const int c = tt & 63, sl = tt >> 6;
        const float* inp = enc ? bufB : bufA;
        const float* w2  = enc ? oe_w2 : se_w2;
        float4 acc = {0.f, 0.f, 0.f, 0.f};
        const float* w = w2 + (size_t)(sl * 128) * 256 + 4 * c;
        #pragma unroll 8
        for (int k = 0; k < 128; ++k)
            fma4_(acc, inp[sl * 128 + k], *(const float4*)(w + (size_t)k * 256));
        part4[enc * 256 + tt] = acc;
    }
    __syncthreads();
    if (t < 64) {
        float4 v = part4[t];
        #pragma unroll
        for (int sl = 1; sl < 4; ++sl) { const float4 p = part4[sl * 64 + t];
            v.x += p.x; v.y += p.y; v.z += p.z; v.w += p.w; }
        const float4 bb = *(const float4*)(se_b2 + 4 * t);
        float4 r; r.x = fmaxf(v.x + bb.x, 0.f); r.y = fmaxf(v.y + bb.y, 0.f);
        r.z = fmaxf(v.z + bb.z, 0.f); r.w = fmaxf(v.w + bb.w, 0.f);
        *(float4*)(z_ws + b * ZDIM + 4 * t) = r;
    } else if (t < 128) {
        const int c = t - 64;
        float4 v = part4[256 + c];
        #pragma unroll
        for (int sl = 1; sl < 4; ++sl) { const float4 p = part4[256 + sl * 64 + c];
            v.x += p.x; v.y += p.y; v.z += p.z; v.w += p.w; }
        const float4 bb = *(const float4*)(oe_b2 + 4 * c);
        float4 r; r.x = fmaxf(v.x + bb.x, 0.f); r.y = fmaxf(v.y + bb.y, 0.f);
        r.z = fmaxf(v.z + bb.z, 0.f); r.w = fmaxf(v.w + bb.w, 0.f);
        *(float4*)(z_ws + b * ZDIM + 256 + 4 * c) = r;
    }
}

// ================= fp32 fallback path (ws too small) =================
__global__ void __launch_bounds__(256)
matvec_f32(const float* __restrict__ W, const float* __restrict__ z_ws,
           const float* __restrict__ pred_bias, float* __restrict__ g_ws)
{
    const int b = blockIdx.x >> 5, chunk = blockIdx.x & 31;
    const int wave = threadIdx.x >> 6, lane = threadIdx.x & 63;
    const int row0 = chunk * 64 + wave * 16;
    const float* zb = z_ws + b * ZDIM;
    const float biasv = (lane < 16) ? pred_bias[b * GDIM + row0 + lane] : 0.f;
    const int l4 = lane * 4;
    const float4 z0 = *(const float4*)(zb + l4);
    const float4 z1 = *(const float4*)(zb + 256 + l4);
    const float4 z2 = *(const float4*)(zb + 512 + l4);
    const float4 z3 = *(const float4*)(zb + 768 + l4);
    const float4 z4 = *(const float4*)(zb + 1024 + l4);
    const char* wb = (const char*)W + (size_t)b * GDIM * ZDIM * 4;

    #define ISSUE(p, B) { const char* a_ = wb + (size_t)(row0 + 2 * (p)) * (ZDIM * 4) + lane * 16; \
        _Pragma("unroll") for (int i = 0; i < 10; ++i) B[i] = *(const uint4*)(a_ + i * 1024); }

    uint4 bufa[10], bufb[10];
    ISSUE(0, bufa);
    #pragma unroll
    for (int p = 0; p < 8; ++p) {
        uint4* cur = (p & 1) ? bufb : bufa;
        uint4* nxt = (p & 1) ? bufa : bufb;
        if (p < 7) ISSUE(p + 1, nxt);
        float accA = 0.f, accB = 0.f;
        dot4_(cur[0], z0, accA); dot4_(cur[1], z1, accA); dot4_(cur[2], z2, accA);
        dot4_(cur[3], z3, accA); dot4_(cur[4], z4, accA);
        dot4_(cur[5], z0, accB); dot4_(cur[6], z1, accB); dot4_(cur[7], z2, accB);
        dot4_(cur[8], z3, accB); dot4_(cur[9], z4, accB);
        float s0 = accA + __shfl_xor(accA, 32);
        float s1 = accB + __shfl_xor(accB, 32);
        float u = (lane < 32) ? s0 : s1;
        #pragma unroll
        for (int m = 16; m >= 1; m >>= 1) u += __shfl_xor(u, m);
        const float badd = __shfl(biasv, 2 * p + ((lane >= 32) ? 1 : 0), 64);
        if (lane == 0)       g_ws[b * GDIM + row0 + 2 * p]     = u + badd;
        else if (lane == 32) g_ws[b * GDIM + row0 + 2 * p + 1] = u + badd;
    }
    #undef ISSUE
}

extern "C" void kernel_launch(void* const* d_in, const int* in_sizes, int n_in,
                              void* d_out, int out_size, void* d_ws, size_t ws_size,
                              hipStream_t stream) {
    const float* prv = (const float*)d_in[0];
    const float* pq  = (const float*)d_in[1];
    const float* pro = (const float*)d_in[2];
    const float* pqo = (const float*)d_in[3];
    const float* pc  = (const float*)d_in[4];
    const float* trp = (const float*)d_in[5];
    const float* tq  = (const float*)d_in[6];
    const float* irp = (const float*)d_in[7];
    const float* pw  = (const float*)d_in[8];
    const float* pb  = (const float*)d_in[9];
    const float* se_w1 = (const float*)d_in[10]; const float* se_b1 = (const float*)d_in[11];
    const float* se_w2 = (const float*)d_in[12]; const float* se_b2 = (const float*)d_in[13];
    const float* oe_w1 = (const float*)d_in[14]; const float* oe_b1 = (const float*)d_in[15];
    const float* oe_w2 = (const float*)d_in[16]; const float* oe_b2 = (const float*)d_in[17];
    const float* te_w1 = (const float*)d_in[18]; const float* te_b1 = (const float*)d_in[19];
    const float* te_w2 = (const float*)d_in[20]; const float* te_b2 = (const float*)d_in[21];
    const float* de_w1 = (const float*)d_in[22]; const float* de_b1 = (const float*)d_in[23];
    const float* de_w2 = (const float*)d_in[24]; const float* de_b2 = (const float*)d_in[25];
    const float* de_w3 = (const float*)d_in[26]; const float* de_b3 = (const float*)d_in[27];
    float* outp = (float*)d_out;

    const size_t WPACKB = (size_t)BATCH * GDIM * PROW;     // 402.7 MB packed int12
    const size_t AUXB = (size_t)BATCH * (GDIM * 3 + ZDIM + HDIM + 192) * 4
                      + (size_t)9 * BATCH * 512 * 4
                      + (size_t)9 * BATCH * GDIM * 4;
    const bool bf = ws_size >= WPACKB + AUXB;

    char* base = (char*)d_ws;
    float* scale_ws; float* g0_ws; float* z_ws;
    if (bf) {
        scale_ws = (float*)(base + WPACKB);
        g0_ws    = scale_ws + (size_t)BATCH * GDIM;
        z_ws     = g0_ws + (size_t)BATCH * GDIM;
    } else {
        scale_ws = nullptr;
        g0_ws    = nullptr;
        z_ws     = (float*)base;
    }
    float* g_ws    = z_ws + (size_t)BATCH * ZDIM;
    float* c_ws    = g_ws + (size_t)BATCH * GDIM;
    float* car_ws  = c_ws + (size_t)BATCH * HDIM;
    float* enc9_ws = car_ws + (size_t)BATCH * 192;
    float* E_ws    = enc9_ws + (size_t)9 * BATCH * 512;

    initk<<<dim3(BATCH), dim3(512), 0, stream>>>(prv, pq, pro, pqo, pc, tq, irp,
        se_w1, se_b1, se_w2, se_b2, oe_w1, oe_b1, oe_w2, oe_b2,
        te_w1, te_b1, te_w2, te_b2, z_ws, c_ws, car_ws);

    if (bf) {
        enc_past<<<dim3(BATCH, 9), dim3(512), 0, stream>>>(prv, pq, pro, pqo, pc,
            se_w1, se_b1, se_w2, se_b2, oe_w1, oe_b1, oe_w2, oe_b2, enc9_ws);
        matvec0_conv<<<dim3(BATCH * 32), dim3(256), 0, stream>>>(
            pw, z_ws, pb, (unsigned char*)d_ws, scale_ws, g_ws, g0_ws);
        epass<<<dim3(BATCH * 32), dim3(256), 0, stream>>>(
            (const unsigned char*)d_ws, enc9_ws, scale_ws, g0_ws, E_ws);
        for (int s = 0; s < NSTEPS; ++s) {
            if (s >= 1 && s < NPAST) {
                matvecH<<<dim3(BATCH * 32), dim3(256), 0, stream>>>(
                    (const unsigned char*)d_ws, z_ws, scale_ws,
                    E_ws + (size_t)(s - 1) * BATCH * GDIM, g_ws);
            } else if (s >= NPAST) {
                matvec12<<<dim3(BATCH * 32), dim3(256), 0, stream>>>(
                    (const unsigned char*)d_ws, z_ws, scale_ws, g0_ws, g_ws);
            }
            if (s < NPAST - 1) {
                // past steps 0..8: decoder/state provably dead -> LSTM only
                lstmk<<<dim3(BATCH), dim3(512), 0, stream>>>(g_ws, z_ws, c_ws);
            } else {
                stepk<<<dim3(BATCH), dim3(512), 0, stream>>>(prv, pq, pro, pqo, pc, trp, tq,
                    se_w1, se_b1, se_w2, se_b2, oe_w1, oe_b1, oe_w2, oe_b2,
                    de_w1, de_b1, de_w2, de_b2, de_w3, de_b3,
                    outp, z_ws, g_ws, c_ws, car_ws, s, 0);
            }
        }
    } else {
        for (int s = 0; s < NSTEPS; ++s) {
            matvec_f32<<<dim3(BATCH * 32), dim3(256), 0, stream>>>(pw, z_ws, pb, g_ws);
            stepk<<<dim3(BATCH), dim3(512), 0, stream>>>(prv, pq, pro, pqo, pc, trp, tq,
                se_w1, se_b1, se_w2, se_b2, oe_w1, oe_b1, oe_w2, oe_b2,
                de_w1, de_b1, de_w2, de_b2, de_w3, de_b3,
                outp, z_ws, g_ws, c_ws, car_ws, s, 0);
        }
    }
}

// Round 14
// 4048.478 us; speedup vs baseline: 1.2372x; 1.2372x over previous
//
#include <hip/hip_runtime.h>
#include <hip/hip_bf16.h>
#include <math.h>

#define BATCH 128
#define QD 88
#define HDIM 512
#define ZDIM 1280
#define GDIM 2048
#define PROW 1536          // packed bytes per row (quad stride = 4*PROW = 6144)
#define QSTRIDE 6144
#define NPAST 10
#define NTRANS 29
#define NSTEPS (NPAST + NTRANS)
#define OUTD 95
#define POSE_ELEMS (BATCH * 30 * 91)

typedef float f32x4 __attribute__((ext_vector_type(4)));
typedef unsigned int u32x4 __attribute__((ext_vector_type(4)));

__device__ __forceinline__ float sig_(float x) { return 1.0f / (1.0f + expf(-x)); }
__device__ __forceinline__ void dot4_(const uint4 wv, const float4 zv, float& d) {
    const float4 f = *(const float4*)&wv;
    d = fmaf(f.x, zv.x, d); d = fmaf(f.y, zv.y, d);
    d = fmaf(f.z, zv.z, d); d = fmaf(f.w, zv.w, d);
}
__device__ __forceinline__ void fma4_(float4& acc, float x, const float4 w) {
    acc.x = fmaf(x, w.x, acc.x); acc.y = fmaf(x, w.y, acc.y);
    acc.z = fmaf(x, w.z, acc.z); acc.w = fmaf(x, w.w, acc.w);
}
__device__ __forceinline__ unsigned q12_(float w, float inv) {
    const unsigned u = __float2uint_rn(fmaf(w, inv, 2048.0f));
    return (u > 4095u) ? 4095u : u;
}
__device__ __forceinline__ void pack12_(const uint4 a, const uint4 b, float inv,
                                        unsigned& o0, unsigned& o1, unsigned& o2) {
    const unsigned u0 = q12_(__uint_as_float(a.x), inv), u1 = q12_(__uint_as_float(a.y), inv);
    const unsigned u2 = q12_(__uint_as_float(a.z), inv), u3 = q12_(__uint_as_float(a.w), inv);
    const unsigned u4 = q12_(__uint_as_float(b.x), inv), u5 = q12_(__uint_as_float(b.y), inv);
    const unsigned u6 = q12_(__uint_as_float(b.z), inv), u7 = q12_(__uint_as_float(b.w), inv);
    o0 = u0 | (u1 << 12) | (u2 << 24);
    o1 = (u2 >> 8) | (u3 << 4) | (u4 << 16) | (u5 << 28);
    o2 = (u5 >> 4) | (u6 << 8) | (u7 << 20);
}
// signed dot of an 8-weight packet with two float4 z fragments (field - 2048)
__device__ __forceinline__ float dot12_(unsigned d0, unsigned d1, unsigned d2,
                                        const float4 za, const float4 zb) {
    float acc = 0.f;
    acc = fmaf((float)((int)(d0 & 0xFFFu) - 2048), za.x, acc);
    acc = fmaf((float)((int)((d0 >> 12) & 0xFFFu) - 2048), za.y, acc);
    acc = fmaf((float)((int)((d0 >> 24) | ((d1 & 0xFu) << 8)) - 2048), za.z, acc);
    acc = fmaf((float)((int)((d1 >> 4) & 0xFFFu) - 2048), za.w, acc);
    acc = fmaf((float)((int)((d1 >> 16) & 0xFFFu) - 2048), zb.x, acc);
    acc = fmaf((float)((int)((d1 >> 28) | ((d2 & 0xFFu) << 4)) - 2048), zb.y, acc);
    acc = fmaf((float)((int)((d2 >> 8) & 0xFFFu) - 2048), zb.z, acc);
    acc = fmaf((float)((int)(d2 >> 20) - 2048), zb.w, acc);
    return acc;
}
__device__ __forceinline__ float wredmax_(float m) {
    #pragma unroll
    for (int s = 32; s >= 1; s >>= 1) m = fmaxf(m, __shfl_xor(m, s, 64));
    return m;
}
__device__ __forceinline__ float amax4_(const uint4 a, float m) {
    m = fmaxf(m, fabsf(__uint_as_float(a.x))); m = fmaxf(m, fabsf(__uint_as_float(a.y)));
    m = fmaxf(m, fabsf(__uint_as_float(a.z))); m = fmaxf(m, fabsf(__uint_as_float(a.w)));
    return m;
}

// ---- step-0 GEMV over fp32 weights, fused with int12 quantization + static fold ----
__global__ void __launch_bounds__(256)
matvec0_conv(const float* __restrict__ W, const float* __restrict__ z_ws,
             const float* __restrict__ pred_bias, unsigned char* __restrict__ Wp,
             float* __restrict__ scale_ws, float* __restrict__ g_ws, float* __restrict__ g0_ws)
{
    const int b = blockIdx.x >> 5, chunk = blockIdx.x & 31;
    const int wave = threadIdx.x >> 6, lane = threadIdx.x & 63;
    const int row0 = chunk * 64 + wave * 16;
    const float* zb = z_ws + b * ZDIM;
    const float biasv = (lane < 16) ? pred_bias[b * GDIM + row0 + lane] : 0.f;
    const int l4 = lane * 4;
    const float4 z0 = *(const float4*)(zb + l4);
    const float4 z1 = *(const float4*)(zb + 256 + l4);
    const float4 zh = *(const float4*)(zb + 512 + l4);
    const float4 z3 = *(const float4*)(zb + 768 + l4);
    const float4 z4 = *(const float4*)(zb + 1024 + l4);
    const char* wb = (const char*)W + (size_t)b * GDIM * ZDIM * 4;
    char* dstB = (char*)Wp + (size_t)b * GDIM * PROW;

    #define ISSUE(p, B) { const char* a_ = wb + (size_t)(row0 + 2 * (p)) * (ZDIM * 4) + lane * 16; \
        _Pragma("unroll") for (int i = 0; i < 10; ++i) B[i] = *(const uint4*)(a_ + i * 1024); }

    uint4 bufa[10], bufb[10];
    unsigned sst[6], hst[6];
    ISSUE(0, bufa);
    #pragma unroll
    for (int p = 0; p < 8; ++p) {
        uint4* cur = (p & 1) ? bufb : bufa;
        uint4* nxt = (p & 1) ? bufa : bufb;
        if (p < 7) ISSUE(p + 1, nxt);
        float dynA = 0.f, dynB = 0.f, statA = 0.f, statB = 0.f;
        dot4_(cur[0], z0, dynA); dot4_(cur[1], z1, dynA);
        dot4_(cur[2], zh, statA);
        dot4_(cur[3], z3, dynA); dot4_(cur[4], z4, dynA);
        dot4_(cur[5], z0, dynB); dot4_(cur[6], z1, dynB);
        dot4_(cur[7], zh, statB);
        dot4_(cur[8], z3, dynB); dot4_(cur[9], z4, dynB);
        float m0 = 0.f, m1 = 0.f;
        m0 = amax4_(cur[0], m0); m0 = amax4_(cur[1], m0);
        m0 = amax4_(cur[3], m0); m0 = amax4_(cur[4], m0);
        m1 = amax4_(cur[5], m1); m1 = amax4_(cur[6], m1);
        m1 = amax4_(cur[8], m1); m1 = amax4_(cur[9], m1);
        m0 = wredmax_(m0); m1 = wredmax_(m1);
        const float s0 = m0 * (1.f / 2047.f), s1 = m1 * (1.f / 2047.f);
        const float inv0 = (m0 > 0.f) ? 2047.f / m0 : 0.f;
        const float inv1 = (m1 > 0.f) ? 2047.f / m1 : 0.f;
        unsigned s0a, s0b, s0c, h0a, h0b, h0c, s1a, s1b, s1c, h1a, h1b, h1c;
        pack12_(cur[0], cur[1], inv0, s0a, s0b, s0c);
        pack12_(cur[3], cur[4], inv0, h0a, h0b, h0c);
        pack12_(cur[5], cur[6], inv1, s1a, s1b, s1c);
        pack12_(cur[8], cur[9], inv1, h1a, h1b, h1c);
        if ((p & 1) == 0) {
            sst[0] = s0a; sst[1] = s0b; sst[2] = s0c; sst[3] = s1a; sst[4] = s1b; sst[5] = s1c;
            hst[0] = h0a; hst[1] = h0b; hst[2] = h0c; hst[3] = h1a; hst[4] = h1b; hst[5] = h1c;
        } else {
            char* base = dstB + (size_t)((row0 + 2 * p) >> 2) * QSTRIDE + lane * 16;
            u32x4 v;
            v.x = sst[0]; v.y = sst[1]; v.z = sst[2]; v.w = sst[3];
            __builtin_nontemporal_store(v, (u32x4*)(base));
            v.x = sst[4]; v.y = sst[5]; v.z = s0a; v.w = s0b;
            __builtin_nontemporal_store(v, (u32x4*)(base + 1024));
            v.x = s0c; v.y = s1a; v.z = s1b; v.w = s1c;
            __builtin_nontemporal_store(v, (u32x4*)(base + 2048));
            v.x = hst[0]; v.y = hst[1]; v.z = hst[2]; v.w = hst[3];
            __builtin_nontemporal_store(v, (u32x4*)(base + 3072));
            v.x = hst[4]; v.y = hst[5]; v.z = h0a; v.w = h0b;
            __builtin_nontemporal_store(v, (u32x4*)(base + 4096));
            v.x = h0c; v.y = h1a; v.z = h1b; v.w = h1c;
            __builtin_nontemporal_store(v, (u32x4*)(base + 5120));
        }
        if (lane == 0) { scale_ws[b * GDIM + row0 + 2 * p] = s0;
                         scale_ws[b * GDIM + row0 + 2 * p + 1] = s1; }
        float sd0 = dynA + __shfl_xor(dynA, 32);
        float sd1 = dynB + __shfl_xor(dynB, 32);
        float ud = (lane < 32) ? sd0 : sd1;
        float ss0 = statA + __shfl_xor(statA, 32);
        float ss1 = statB + __shfl_xor(statB, 32);
        float us = (lane < 32) ? ss0 : ss1;
        #pragma unroll
        for (int m = 16; m >= 1; m >>= 1) { ud += __shfl_xor(ud, m); us += __shfl_xor(us, m); }
        const float badd = __shfl(biasv, 2 * p + ((lane >= 32) ? 1 : 0), 64);
        if (lane == 0 || lane == 32) {
            const int r = row0 + 2 * p + ((lane >= 32) ? 1 : 0);
            g0_ws[b * GDIM + r] = us + badd;
            g_ws[b * GDIM + r]  = ud + us + badd;
        }
    }
    #undef ISSUE
}

// helper: reduce a row pair (rA,rB) across the wave, add base+scale, write 2 rows
__device__ __forceinline__ void redwrite_(float rA, float rB, int lane,
                                          float g0v, float scv, int idx0,
                                          float* __restrict__ dst, int drow0) {
    const float sA = rA + __shfl_xor(rA, 32);
    const float sB = rB + __shfl_xor(rB, 32);
    float u = (lane < 32) ? sA : sB;
    #pragma unroll
    for (int m = 16; m >= 1; m >>= 1) u += __shfl_xor(u, m);
    const int hilo = (lane >= 32) ? 1 : 0;
    const float badd = __shfl(g0v, idx0 + hilo, 64);
    const float srow = __shfl(scv, idx0 + hilo, 64);
    const float val = badd + srow * u;
    if (lane == 0)       dst[drow0] = val;
    else if (lane == 32) dst[drow0 + 1] = val;
}

// ---- E-pass: E[s][b][row] = g0 + s_row*(W_state . enc[s])  (state blocks only) ----
__global__ void __launch_bounds__(256)
epass(const unsigned char* __restrict__ Wp, const float* __restrict__ enc9,
      const float* __restrict__ scale_ws, const float* __restrict__ g0_ws,
      float* __restrict__ E_ws)
{
    const int b = blockIdx.x >> 5, chunk = blockIdx.x & 31;
    const int wave = threadIdx.x >> 6, lane = threadIdx.x & 63;
    const int row0 = chunk * 64 + wave * 16;
    const int q0 = row0 >> 2;
    const int l4 = lane * 4;
    float4 eA[9], eB[9];
    #pragma unroll
    for (int s = 0; s < 9; ++s) {
        const float* eb = enc9 + ((size_t)s * BATCH + b) * 512;
        eA[s] = *(const float4*)(eb + l4);
        eB[s] = *(const float4*)(eb + 256 + l4);
    }
    const float g0v = (lane < 16) ? g0_ws[b * GDIM + row0 + lane] : 0.f;
    const float scv = (lane < 16) ? scale_ws[b * GDIM + row0 + lane] : 0.f;
    const char* wb = (const char*)Wp + (size_t)b * GDIM * PROW;

    #define ISSUE(qq, B) { const char* a_ = wb + (size_t)(q0 + (qq)) * QSTRIDE + lane * 16; \
        B[0] = __builtin_nontemporal_load((const u32x4*)(a_)); \
        B[1] = __builtin_nontemporal_load((const u32x4*)(a_ + 1024)); \
        B[2] = __builtin_nontemporal_load((const u32x4*)(a_ + 2048)); }

    u32x4 bufa[3], bufb[3];
    ISSUE(0, bufa);
    #pragma unroll
    for (int qq = 0; qq < 4; ++qq) {
        u32x4* cur = (qq & 1) ? bufb : bufa;
        u32x4* nxt = (qq & 1) ? bufa : bufb;
        if (qq < 3) ISSUE(qq + 1, nxt);
        #pragma unroll
        for (int s = 0; s < 9; ++s) {
            const float r0 = dot12_(cur[0].x, cur[0].y, cur[0].z, eA[s], eB[s]);
            const float r1 = dot12_(cur[0].w, cur[1].x, cur[1].y, eA[s], eB[s]);
            const float r2 = dot12_(cur[1].z, cur[1].w, cur[2].x, eA[s], eB[s]);
            const float r3 = dot12_(cur[2].y, cur[2].z, cur[2].w, eA[s], eB[s]);
            float* dst = E_ws + ((size_t)s * BATCH + b) * GDIM;
            redwrite_(r0, r1, lane, g0v, scv, 4 * qq,     dst, row0 + 4 * qq);
            redwrite_(r2, r3, lane, g0v, scv, 4 * qq + 2, dst, row0 + 4 * qq + 2);
        }
    }
    #undef ISSUE
}

// ---- past-step GEMV (s=1..9): gates = E[s] + s_row*(W_h . h)  (h blocks, L3) ----
__global__ void __launch_bounds__(256)
matvecH(const unsigned char* __restrict__ Wp, const float* __restrict__ z_ws,
        const float* __restrict__ scale_ws, const float* __restrict__ Es,
        float* __restrict__ g_ws)
{
    const int b = blockIdx.x >> 5, chunk = blockIdx.x & 31;
    const int wave = threadIdx.x >> 6, lane = threadIdx.x & 63;
    const int row0 = chunk * 64 + wave * 16;
    const int q0 = row0 >> 2;
    const float* zb = z_ws + b * ZDIM;
    const int l4 = lane * 4;
    const float4 z3 = *(const float4*)(zb + 768 + l4);
    const float4 z4 = *(const float4*)(zb + 1024 + l4);
    const float Ev  = (lane < 16) ? Es[b * GDIM + row0 + lane] : 0.f;
    const float scv = (lane < 16) ? scale_ws[b * GDIM + row0 + lane] : 0.f;
    const char* wb = (const char*)Wp + (size_t)b * GDIM * PROW;

    #define ISSUE(qq, B) { const char* a_ = wb + (size_t)(q0 + (qq)) * QSTRIDE + 3072 + lane * 16; \
        B[0] = *(const u32x4*)(a_); \
        B[1] = *(const u32x4*)(a_ + 1024); \
        B[2] = *(const u32x4*)(a_ + 2048); }

    u32x4 buf0[3], buf1[3], buf2[3];
    ISSUE(0, buf0);
    ISSUE(1, buf1);
    #pragma unroll
    for (int qq = 0; qq < 4; ++qq) {
        u32x4* cur = (qq % 3 == 0) ? buf0 : (qq % 3 == 1) ? buf1 : buf2;
        u32x4* nxt = ((qq + 2) % 3 == 0) ? buf0 : ((qq + 2) % 3 == 1) ? buf1 : buf2;
        if (qq < 2) ISSUE(qq + 2, nxt);
        const float r0 = dot12_(cur[0].x, cur[0].y, cur[0].z, z3, z4);
        const float r1 = dot12_(cur[0].w, cur[1].x, cur[1].y, z3, z4);
        const float r2 = dot12_(cur[1].z, cur[1].w, cur[2].x, z3, z4);
        const float r3 = dot12_(cur[2].y, cur[2].z, cur[2].w, z3, z4);
        float* dst = g_ws + b * GDIM;
        redwrite_(r0, r1, lane, Ev, scv, 4 * qq,     dst, row0 + 4 * qq);
        redwrite_(r2, r3, lane, Ev, scv, 4 * qq + 2, dst, row0 + 4 * qq + 2);
    }
    #undef ISSUE
}

// ---- transition-step GEMV over int12 quad layout (NT loads: stream past L3) ----
__global__ void __launch_bounds__(256)
matvec12(const unsigned char* __restrict__ Wp, const float* __restrict__ z_ws,
         const float* __restrict__ scale_ws, const float* __restrict__ g0_ws,
         float* __restrict__ g_ws)
{
    const int b = blockIdx.x >> 5, chunk = blockIdx.x & 31;
    const int wave = threadIdx.x >> 6, lane = threadIdx.x & 63;
    const int row0 = chunk * 64 + wave * 16;
    const int q0 = row0 >> 2;
    const float* zb = z_ws + b * ZDIM;
    const int l4 = lane * 4;
    const float4 z0 = *(const float4*)(zb + l4);
    const float4 z1 = *(const float4*)(zb + 256 + l4);
    const float4 z3 = *(const float4*)(zb + 768 + l4);
    const float4 z4 = *(const float4*)(zb + 1024 + l4);
    const float g0v = (lane < 16) ? g0_ws[b * GDIM + row0 + lane] : 0.f;
    const float scv = (lane < 16) ? scale_ws[b * GDIM + row0 + lane] : 0.f;
    const char* wb = (const char*)Wp + (size_t)b * GDIM * PROW;

    #define ISSUE(qq, B) { const char* a_ = wb + (size_t)(q0 + (qq)) * QSTRIDE + lane * 16; \
        B[0] = __builtin_nontemporal_load((const u32x4*)(a_)); \
        B[1] = __builtin_nontemporal_load((const u32x4*)(a_ + 1024)); \
        B[2] = __builtin_nontemporal_load((const u32x4*)(a_ + 2048)); \
        B[3] = __builtin_nontemporal_load((const u32x4*)(a_ + 3072)); \
        B[4] = __builtin_nontemporal_load((const u32x4*)(a_ + 4096)); \
        B[5] = __builtin_nontemporal_load((const u32x4*)(a_ + 5120)); }

    u32x4 buf0[6], buf1[6], buf2[6];
    ISSUE(0, buf0);
    ISSUE(1, buf1);
    #pragma unroll
    for (int qq = 0; qq < 4; ++qq) {
        u32x4* cur = (qq % 3 == 0) ? buf0 : (qq % 3 == 1) ? buf1 : buf2;
        u32x4* nxt = ((qq + 2) % 3 == 0) ? buf0 : ((qq + 2) % 3 == 1) ? buf1 : buf2;
        if (qq < 2) ISSUE(qq + 2, nxt);
        const float r0 = dot12_(cur[0].x, cur[0].y, cur[0].z, z0, z1)
                       + dot12_(cur[3].x, cur[3].y, cur[3].z, z3, z4);
        const float r1 = dot12_(cur[0].w, cur[1].x, cur[1].y, z0, z1)
                       + dot12_(cur[3].w, cur[4].x, cur[4].y, z3, z4);
        const float r2 = dot12_(cur[1].z, cur[1].w, cur[2].x, z0, z1)
                       + dot12_(cur[4].z, cur[4].w, cur[5].x, z3, z4);
        const float r3 = dot12_(cur[2].y, cur[2].z, cur[2].w, z0, z1)
                       + dot12_(cur[5].y, cur[5].z, cur[5].w, z3, z4);
        float* dst = g_ws + b * GDIM;
        redwrite_(r0, r1, lane, g0v, scv, 4 * qq,     dst, row0 + 4 * qq);
        redwrite_(r2, r3, lane, g0v, scv, 4 * qq + 2, dst, row0 + 4 * qq + 2);
    }
    #undef ISSUE
}

// ---- LSTM-only step for past steps 0..8 (decoder provably dead there) ----
__global__ void __launch_bounds__(512)
lstmk(const float* __restrict__ g_ws, float* __restrict__ z_ws, float* __restrict__ c_ws)
{
    const int b = blockIdx.x, t = threadIdx.x;
    const float* g = g_ws + b * GDIM;
    const float ig = g[t], fg = g[512 + t], gg = g[1024 + t], og = g[1536 + t];
    const float c2 = sig_(fg) * c_ws[b * HDIM + t] + sig_(ig) * tanhf(gg);
    c_ws[b * HDIM + t] = c2;
    z_ws[b * ZDIM + 768 + t] = sig_(og) * tanhf(c2);
}

// ---------------- init: state=0, h_target, step-0 encoders, glob presum ----------------
__global__ void __launch_bounds__(512)
initk(const float* __restrict__ past_root_vel, const float* __restrict__ past_quats,
      const float* __restrict__ past_root_offset, const float* __restrict__ past_quat_offset,
      const float* __restrict__ past_contacts, const float* __restrict__ target_quats,
      const float* __restrict__ init_root_pos,
      const float* __restrict__ se_w1, const float* __restrict__ se_b1,
      const float* __restrict__ se_w2, const float* __restrict__ se_b2,
      const float* __restrict__ oe_w1, const float* __restrict__ oe_b1,
      const float* __restrict__ oe_w2, const float* __restrict__ oe_b2,
      const float* __restrict__ te_w1, const float* __restrict__ te_b1,
      const float* __restrict__ te_w2, const float* __restrict__ te_b2,
      float* __restrict__ z_ws, float* __restrict__ c_ws, float* __restrict__ car_ws)
{
    const int b = blockIdx.x, t = threadIdx.x;
    __shared__ float tq[QD], bufA[512], bufB[512], sv[95], ov[91];

    if (t < 192) {
        float v = 0.f;
        if (t < 3) {
            v = init_root_pos[b * 3 + t];
            // glob after past steps 0..8 (lstmk path skips the per-step accumulation)
            for (int s = 0; s < NPAST - 1; ++s) v += past_root_vel[(b * NPAST + s) * 3 + t];
        }
        car_ws[b * 192 + t] = v;
    }
    c_ws[b * HDIM + t] = 0.f;
    z_ws[b * ZDIM + 768 + t] = 0.f;
    if (t < QD) tq[t] = target_quats[b * QD + t];
    if (t < 4)  sv[t] = past_contacts[b * NPAST * 4 + t];
    if (t < QD) { sv[4 + t] = past_quats[b * NPAST * QD + t];
                  ov[3 + t] = past_quat_offset[b * NPAST * QD + t]; }
    if (t < 3)  { sv[92 + t] = past_root_vel[b * NPAST * 3 + t];
                  ov[t]      = past_root_offset[b * NPAST * 3 + t]; }
    __syncthreads();
    {
        float a = te_b1[t];
        #pragma unroll 8
        for (int i = 0; i < QD; ++i) a = fmaf(tq[i], te_w1[i * 512 + t], a);
        bufA[t] = fmaxf(a, 0.f);
    }
    __syncthreads();
    if (t < 256) {
        float a = te_b2[t];
        #pragma unroll 8
        for (int i = 0; i < 512; ++i) a = fmaf(bufA[i], te_w2[i * 256 + t], a);
        z_ws[b * ZDIM + 512 + t] = fmaxf(a, 0.f);
    }
    __syncthreads();
    {
        float aS = se_b1[t], aO = oe_b1[t];
        #pragma unroll 8
        for (int i = 0; i < 91; ++i) { aS = fmaf(sv[i], se_w1[i * 512 + t], aS);
                                       aO = fmaf(ov[i], oe_w1[i * 512 + t], aO); }
        #pragma unroll
        for (int i = 91; i < 95; ++i) aS = fmaf(sv[i], se_w1[i * 512 + t], aS);
        bufA[t] = fmaxf(aS, 0.f);
        bufB[t] = fmaxf(aO, 0.f);
    }
    __syncthreads();
    if (t < 256) {
        float a = se_b2[t];
        #pragma unroll 8
        for (int i = 0; i < 512; ++i) a = fmaf(bufA[i], se_w2[i * 256 + t], a);
        z_ws[b * ZDIM + t] = fmaxf(a, 0.f);
    } else {
        const int j = t - 256;
        float a = oe_b2[j];
        #pragma unroll 8
        for (int i = 0; i < 512; ++i) a = fmaf(bufB[i], oe_w2[i * 256 + j], a);
        z_ws[b * ZDIM + 256 + j] = fmaxf(a, 0.f);
    }
}

// ---- batch-encode past steps 1..9 -> enc9[(s-1)*BATCH + b][512] ----
__global__ void __launch_bounds__(512)
enc_past(const float* __restrict__ past_root_vel, const float* __restrict__ past_quats,
         const float* __restrict__ past_root_offset, const float* __restrict__ past_quat_offset,
         const float* __restrict__ past_contacts,
         const float* __restrict__ se_w1, const float* __restrict__ se_b1,
         const float* __restrict__ se_w2, const float* __restrict__ se_b2,
         const float* __restrict__ oe_w1, const float* __restrict__ oe_b1,
         const float* __restrict__ oe_w2, const float* __restrict__ oe_b2,
         float* __restrict__ enc9)
{
    const int b = blockIdx.x, t = threadIdx.x;
    const int s = blockIdx.y + 1;
    __shared__ float bufA[512], bufB[512], sv[95], ov[91];

    if (t < 4)  sv[t] = past_contacts[(b * NPAST + s) * 4 + t];
    if (t < QD) { sv[4 + t] = past_quats[(b * NPAST + s) * QD + t];
                  ov[3 + t] = past_quat_offset[(b * NPAST + s) * QD + t]; }
    if (t < 3)  { sv[92 + t] = past_root_vel[(b * NPAST + s) * 3 + t];
                  ov[t]      = past_root_offset[(b * NPAST + s) * 3 + t]; }
    __syncthreads();
    {
        float aS = se_b1[t], aO = oe_b1[t];
        #pragma unroll 8
        for (int i = 0; i < 91; ++i) { aS = fmaf(sv[i], se_w1[i * 512 + t], aS);
                                       aO = fmaf(ov[i], oe_w1[i * 512 + t], aO); }
        #pragma unroll
        for (int i = 91; i < 95; ++i) aS = fmaf(sv[i], se_w1[i * 512 + t], aS);
        bufA[t] = fmaxf(aS, 0.f);
        bufB[t] = fmaxf(aO, 0.f);
    }
    __syncthreads();
    float* dst = enc9 + ((size_t)(s - 1) * BATCH + b) * 512;
    if (t < 256) {
        float a = se_b2[t];
        #pragma unroll 8
        for (int i = 0; i < 512; ++i) a = fmaf(bufA[i], se_w2[i * 256 + t], a);
        dst[t] = fmaxf(a, 0.f);
    } else {
        const int j = t - 256;
        float a = oe_b2[j];
        #pragma unroll 8
        for (int i = 0; i < 512; ++i) a = fmaf(bufB[i], oe_w2[i * 256 + j], a);
        dst[256 + j] = fmaxf(a, 0.f);
    }
}

// ---------------- per-step: LSTM + decoder + state update + next encoders ----------------
__global__ void __launch_bounds__(512)
stepk(const float* __restrict__ past_root_vel, const float* __restrict__ past_quats,
      const float* __restrict__ past_root_offset, const float* __restrict__ past_quat_offset,
      const float* __restrict__ past_contacts, const float* __restrict__ target_root_pos,
      const float* __restrict__ target_quats,
      const float* __restrict__ se_w1, const float* __restrict__ se_b1,
      const float* __restrict__ se_w2, const float* __restrict__ se_b2,
      const float* __restrict__ oe_w1, const float* __restrict__ oe_b1,
      const float* __restrict__ oe_w2, const float* __restrict__ oe_b2,
      const float* __restrict__ de_w1, const float* __restrict__ de_b1,
      const float* __restrict__ de_w2, const float* __restrict__ de_b2,
      const float* __restrict__ de_w3, const float* __restrict__ de_b3,
      float* __restrict__ out, float* __restrict__ z_ws, const float* __restrict__ g_ws,
      float* __restrict__ c_ws, float* __restrict__ car_ws, int s, int skip_enc)
{
    const int b = blockIdx.x, t = threadIdx.x;
    __shared__ float4 part4[512];
    __shared__ __align__(16) float h2s[HDIM], bufA[512], bufB[512], d2[256];
    __shared__ float outv[OUTD], nq[QD], sv[95], ov[91], carryL[192], tq[QD], trp[3];
    __shared__ float rvn[3], globn[3], contn[4];

    if (t < 192) carryL[t] = car_ws[b * 192 + t];
    if (t < QD) tq[t] = target_quats[b * QD + t];
    if (t < 3)  trp[t] = target_root_pos[b * 3 + t];

    {
        const float* g = g_ws + b * GDIM;
        const float ig = g[t], fg = g[512 + t], gg = g[1024 + t], og = g[1536 + t];
        const float c2 = sig_(fg) * c_ws[b * HDIM + t] + sig_(ig) * tanhf(gg);
        c_ws[b * HDIM + t] = c2;
        const float h2 = sig_(og) * tanhf(c2);
        h2s[t] = h2;
        z_ws[b * ZDIM + 768 + t] = h2;
    }
    __syncthreads();
    {
        const int c = t & 127, s4 = t >> 7;
        float4 acc = {0.f, 0.f, 0.f, 0.f};
        const float* w = de_w1 + (size_t)(s4 * 128) * 512 + 4 * c;
        #pragma unroll 8
        for (int k = 0; k < 128; ++k)
            fma4_(acc, h2s[s4 * 128 + k], *(const float4*)(w + (size_t)k * 512));
        part4[t] = acc;
    }
    __syncthreads();
    if (t < 128) {
        float4 v = part4[t];
        #pragma unroll
        for (int s4 = 1; s4 < 4; ++s4) { const float4 p = part4[s4 * 128 + t];
            v.x += p.x; v.y += p.y; v.z += p.z; v.w += p.w; }
        const float4 bb = *(const float4*)(de_b1 + 4 * t);
        float4 r; r.x = fmaxf(v.x + bb.x, 0.f); r.y = fmaxf(v.y + bb.y, 0.f);
        r.z = fmaxf(v.z + bb.z, 0.f); r.w = fmaxf(v.w + bb.w, 0.f);
        *(float4*)&bufA[4 * t] = r;
    }
    __syncthreads();
    {
        const int c = t & 63, s8 = t >> 6;
        float4 acc = {0.f, 0.f, 0.f, 0.f};
        const float* w = de_w2 + (size_t)(s8 * 64) * 256 + 4 * c;
        #pragma unroll 8
        for (int k = 0; k < 64; ++k)
            fma4_(acc, bufA[s8 * 64 + k], *(const float4*)(w + (size_t)k * 256));
        part4[t] = acc;
    }
    __syncthreads();
    if (t < 64) {
        float4 v = part4[t];
        #pragma unroll
        for (int s8 = 1; s8 < 8; ++s8) { const float4 p = part4[s8 * 64 + t];
            v.x += p.x; v.y += p.y; v.z += p.z; v.w += p.w; }
        const float4 bb = *(const float4*)(de_b2 + 4 * t);
        float4 r; r.x = fmaxf(v.x + bb.x, 0.f); r.y = fmaxf(v.y + bb.y, 0.f);
        r.z = fmaxf(v.z + bb.z, 0.f); r.w = fmaxf(v.w + bb.w, 0.f);
        *(float4*)&d2[4 * t] = r;
    }
    __syncthreads();
    if (t < OUTD) {
        float acc = de_b3[t];
        #pragma unroll 16
        for (int i = 0; i < 256; ++i) acc = fmaf(d2[i], de_w3[i * OUTD + t], acc);
        outv[t] = acc;
    }
    __syncthreads();

    const bool pastS = (s < NPAST);
    if (t < QD) {
        const float qin = pastS ? past_quats[(b * NPAST + s) * QD + t] : carryL[10 + t];
        nq[t] = outv[t] + qin;
    }
    __syncthreads();
    if (t < 22) {
        const float a = nq[4 * t], b2 = nq[4 * t + 1], c3 = nq[4 * t + 2], d4 = nq[4 * t + 3];
        const float inv = 1.f / fmaxf(sqrtf(a * a + b2 * b2 + c3 * c3 + d4 * d4), 1e-12f);
        nq[4 * t] = a * inv; nq[4 * t + 1] = b2 * inv; nq[4 * t + 2] = c3 * inv; nq[4 * t + 3] = d4 * inv;
    }
    if (t < 3) {
        const float rin = pastS ? past_root_vel[(b * NPAST + s) * 3 + t] : carryL[3 + t];
        const float nrv = outv[88 + t] + rin;
        const float g = carryL[t] + (pastS ? rin : nrv);
        rvn[t] = nrv; globn[t] = g;
    }
    if (t < 4) contn[t] = sig_(outv[91 + t]);
    __syncthreads();

    if (t < 3) { car_ws[b * 192 + t] = globn[t]; car_ws[b * 192 + 3 + t] = rvn[t];
                 car_ws[b * 192 + 186 + t] = globn[t] - trp[t]; }
    if (t < 4) car_ws[b * 192 + 6 + t] = contn[t];
    if (t < QD) { car_ws[b * 192 + 10 + t] = nq[t]; car_ws[b * 192 + 98 + t] = nq[t] - tq[t]; }
    if (s == NPAST - 1) {
        const size_t pb = (size_t)b * 30 * 91;
        if (t < 3)  out[pb + t] = rvn[t];
        if (t < QD) out[pb + 3 + t] = nq[t];
        if (t < 4)  out[POSE_ELEMS + (size_t)b * 30 * 4 + t] = contn[t];
    } else if (!pastS) {
        const int k = s - NPAST + 1;
        const size_t pb = ((size_t)b * 30 + k) * 91;
        if (t < 3)  out[pb + t] = globn[t];
        if (t < QD) out[pb + 3 + t] = nq[t];
        if (t < 4)  out[POSE_ELEMS + ((size_t)b * 30 + k) * 4 + t] = contn[t];
    }
    if (s == NSTEPS - 1) return;
    if (skip_enc) return;

    const int nx = s + 1;
    if (nx < NPAST) {
        if (t < 4)  sv[t] = past_contacts[(b * NPAST + nx) * 4 + t];
        if (t < QD) { sv[4 + t] = past_quats[(b * NPAST + nx) * QD + t];
                      ov[3 + t] = past_quat_offset[(b * NPAST + nx) * QD + t]; }
        if (t < 3)  { sv[92 + t] = past_root_vel[(b * NPAST + nx) * 3 + t];
                      ov[t]      = past_root_offset[(b * NPAST + nx) * 3 + t]; }
    } else {
        if (t < 4)  sv[t] = contn[t];
        if (t < QD) { sv[4 + t] = nq[t]; ov[3 + t] = nq[t] - tq[t]; }
        if (t < 3)  { sv[92 + t] = rvn[t]; ov[t] = globn[t] - trp[t]; }
    }
    __syncthreads();
    {
        const int tt = t & 255, enc = t >> 8;
        const int c = tt & 127, sl = tt >> 7;
        const float* inp = enc ? ov : sv;
        const float* w1  = enc ? oe_w1 : se_w1;
        const int nin  = enc ? 91 : 95;
        const int half = enc ? 46 : 48;
        const int i0 = sl * half;
        const int iend = (i0 + half < nin) ? (i0 + half) : nin;
        float4 acc = {0.f, 0.f, 0.f, 0.f};
        #pragma unroll 8
        for (int k = 0; k < 48; ++k) {
            const int i = i0 + k;
            if (i < iend) fma4_(acc, inp[i], *(const float4*)(w1 + (size_t)i * 512 + 4 * c));
        }
        part4[enc * 256 + tt] = acc;
    }
    __syncthreads();
    if (t < 128) {
        const float4 a = part4[t], b2 = part4[128 + t];
        const float4 bb = *(const float4*)(se_b1 + 4 * t);
        float4 r; r.x = fmaxf(a.x + b2.x + bb.x, 0.f); r.y = fmaxf(a.y + b2.y + bb.y, 0.f);
        r.z = fmaxf(a.z + b2.z + bb.z, 0.f); r.w = fmaxf(a.w + b2.w + bb.w, 0.f);
        *(float4*)&bufA[4 * t] = r;
    } else if (t < 256) {
        const int c = t - 128;
        const float4 a = part4[256 + c], b2 = part4[384 + c];
        const float4 bb = *(const float4*)(oe_b1 + 4 * c);
        float4 r; r.x = fmaxf(a.x + b2.x + bb.x, 0.f); r.y = fmaxf(a.y + b2.y + bb.y, 0.f);
        r.z = fmaxf(a.z + b2.z + bb.z, 0.f); r.w = fmaxf(a.w + b2.w + bb.w, 0.f);
        *(float4*)&bufB[4 * c] = r;
    }
    __syncthreads();
    {
        const int tt = t & 255, enc = t >> 8;
        const int c = tt & 63, sl = tt >> 6;
        const float* inp = enc ? bufB : bufA;
        const float* w2  = enc ? oe_w2 : se_w2;
        float4 acc = {0.f, 0.f, 0.f, 0.f};
        const float* w = w2 + (size_t)(sl * 128) * 256 + 4 * c;
        #pragma unroll 8
        for (int k = 0; k < 128; ++k)
            fma4_(acc, inp[sl * 128 + k], *(const float4*)(w + (size_t)k * 256));
        part4[enc * 256 + tt] = acc;
    }
    __syncthreads();
    if (t < 64) {
        float4 v = part4[t];
        #pragma unroll
        for (int sl = 1; sl < 4; ++sl) { const float4 p = part4[sl * 64 + t];
            v.x += p.x; v.y += p.y; v.z += p.z; v.w += p.w; }
        const float4 bb = *(const float4*)(se_b2 + 4 * t);
        float4 r; r.x = fmaxf(v.x + bb.x, 0.f); r.y = fmaxf(v.y + bb.y, 0.f);
        r.z = fmaxf(v.z + bb.z, 0.f); r.w = fmaxf(v.w + bb.w, 0.f);
        *(float4*)(z_ws + b * ZDIM + 4 * t) = r;
    } else if (t < 128) {
        const int c = t - 64;
        float4 v = part4[256 + c];
        #pragma unroll
        for (int sl = 1; sl < 4; ++sl) { const float4 p = part4[256 + sl * 64 + c];
            v.x += p.x; v.y += p.y; v.z += p.z; v.w += p.w; }
        const float4 bb = *(const float4*)(oe_b2 + 4 * c);
        float4 r; r.x = fmaxf(v.x + bb.x, 0.f); r.y = fmaxf(v.y + bb.y, 0.f);
        r.z = fmaxf(v.z + bb.z, 0.f); r.w = fmaxf(v.w + bb.w, 0.f);
        *(float4*)(z_ws + b * ZDIM + 256 + 4 * c) = r;
    }
}

// ================= fp32 fallback path (ws too small) =================
__global__ void __launch_bounds__(256)
matvec_f32(const float* __restrict__ W, const float* __restrict__ z_ws,
           const float* __restrict__ pred_bias, float* __restrict__ g_ws)
{
    const int b = blockIdx.x >> 5, chunk = blockIdx.x & 31;
    const int wave = threadIdx.x >> 6, lane = threadIdx.x & 63;
    const int row0 = chunk * 64 + wave * 16;
    const float* zb = z_ws + b * ZDIM;
    const float biasv = (lane < 16) ? pred_bias[b * GDIM + row0 + lane] : 0.f;
    const int l4 = lane * 4;
    const float4 z0 = *(const float4*)(zb + l4);
    const float4 z1 = *(const float4*)(zb + 256 + l4);
    const float4 z2 = *(const float4*)(zb + 512 + l4);
    const float4 z3 = *(const float4*)(zb + 768 + l4);
    const float4 z4 = *(const float4*)(zb + 1024 + l4);
    const char* wb = (const char*)W + (size_t)b * GDIM * ZDIM * 4;

    #define ISSUE(p, B) { const char* a_ = wb + (size_t)(row0 + 2 * (p)) * (ZDIM * 4) + lane * 16; \
        _Pragma("unroll") for (int i = 0; i < 10; ++i) B[i] = *(const uint4*)(a_ + i * 1024); }

    uint4 bufa[10], bufb[10];
    ISSUE(0, bufa);
    #pragma unroll
    for (int p = 0; p < 8; ++p) {
        uint4* cur = (p & 1) ? bufb : bufa;
        uint4* nxt = (p & 1) ? bufa : bufb;
        if (p < 7) ISSUE(p + 1, nxt);
        float accA = 0.f, accB = 0.f;
        dot4_(cur[0], z0, accA); dot4_(cur[1], z1, accA); dot4_(cur[2], z2, accA);
        dot4_(cur[3], z3, accA); dot4_(cur[4], z4, accA);
        dot4_(cur[5], z0, accB); dot4_(cur[6], z1, accB); dot4_(cur[7], z2, accB);
        dot4_(cur[8], z3, accB); dot4_(cur[9], z4, accB);
        float s0 = accA + __shfl_xor(accA, 32);
        float s1 = accB + __shfl_xor(accB, 32);
        float u = (lane < 32) ? s0 : s1;
        #pragma unroll
        for (int m = 16; m >= 1; m >>= 1) u += __shfl_xor(u, m);
        const float badd = __shfl(biasv, 2 * p + ((lane >= 32) ? 1 : 0), 64);
        if (lane == 0)       g_ws[b * GDIM + row0 + 2 * p]     = u + badd;
        else if (lane == 32) g_ws[b * GDIM + row0 + 2 * p + 1] = u + badd;
    }
    #undef ISSUE
}

extern "C" void kernel_launch(void* const* d_in, const int* in_sizes, int n_in,
                              void* d_out, int out_size, void* d_ws, size_t ws_size,
                              hipStream_t stream) {
    const float* prv = (const float*)d_in[0];
    const float* pq  = (const float*)d_in[1];
    const float* pro = (const float*)d_in[2];
    const float* pqo = (const float*)d_in[3];
    const float* pc  = (const float*)d_in[4];
    const float* trp = (const float*)d_in[5];
    const float* tq  = (const float*)d_in[6];
    const float* irp = (const float*)d_in[7];
    const float* pw  = (const float*)d_in[8];
    const float* pb  = (const float*)d_in[9];
    const float* se_w1 = (const float*)d_in[10]; const float* se_b1 = (const float*)d_in[11];
    const float* se_w2 = (const float*)d_in[12]; const float* se_b2 = (const float*)d_in[13];
    const float* oe_w1 = (const float*)d_in[14]; const float* oe_b1 = (const float*)d_in[15];
    const float* oe_w2 = (const float*)d_in[16]; const float* oe_b2 = (const float*)d_in[17];
    const float* te_w1 = (const float*)d_in[18]; const float* te_b1 = (const float*)d_in[19];
    const float* te_w2 = (const float*)d_in[20]; const float* te_b2 = (const float*)d_in[21];
    const float* de_w1 = (const float*)d_in[22]; const float* de_b1 = (const float*)d_in[23];
    const float* de_w2 = (const float*)d_in[24]; const float* de_b2 = (const float*)d_in[25];
    const float* de_w3 = (const float*)d_in[26]; const float* de_b3 = (const float*)d_in[27];
    float* outp = (float*)d_out;

    const size_t WPACKB = (size_t)BATCH * GDIM * PROW;     // 402.7 MB packed int12
    const size_t AUXB = (size_t)BATCH * (GDIM * 3 + ZDIM + HDIM + 192) * 4
                      + (size_t)9 * BATCH * 512 * 4
                      + (size_t)9 * BATCH * GDIM * 4;
    const bool bf = ws_size >= WPACKB + AUXB;

    char* base = (char*)d_ws;
    float* scale_ws; float* g0_ws; float* z_ws;
    if (bf) {
        scale_ws = (float*)(base + WPACKB);
        g0_ws    = scale_ws + (size_t)BATCH * GDIM;
        z_ws     = g0_ws + (size_t)BATCH * GDIM;
    } else {
        scale_ws = nullptr;
        g0_ws    = nullptr;
        z_ws     = (float*)base;
    }
    float* g_ws    = z_ws + (size_t)BATCH * ZDIM;
    float* c_ws    = g_ws + (size_t)BATCH * GDIM;
    float* car_ws  = c_ws + (size_t)BATCH * HDIM;
    float* enc9_ws = car_ws + (size_t)BATCH * 192;
    float* E_ws    = enc9_ws + (size_t)9 * BATCH * 512;

    initk<<<dim3(BATCH), dim3(512), 0, stream>>>(prv, pq, pro, pqo, pc, tq, irp,
        se_w1, se_b1, se_w2, se_b2, oe_w1, oe_b1, oe_w2, oe_b2,
        te_w1, te_b1, te_w2, te_b2, z_ws, c_ws, car_ws);

    if (bf) {
        enc_past<<<dim3(BATCH, 9), dim3(512), 0, stream>>>(prv, pq, pro, pqo, pc,
            se_w1, se_b1, se_w2, se_b2, oe_w1, oe_b1, oe_w2, oe_b2, enc9_ws);
        matvec0_conv<<<dim3(BATCH * 32), dim3(256), 0, stream>>>(
            pw, z_ws, pb, (unsigned char*)d_ws, scale_ws, g_ws, g0_ws);
        epass<<<dim3(BATCH * 32), dim3(256), 0, stream>>>(
            (const unsigned char*)d_ws, enc9_ws, scale_ws, g0_ws, E_ws);
        for (int s = 0; s < NSTEPS; ++s) {
            if (s >= 1 && s < NPAST) {
                matvecH<<<dim3(BATCH * 32), dim3(256), 0, stream>>>(
                    (const unsigned char*)d_ws, z_ws, scale_ws,
                    E_ws + (size_t)(s - 1) * BATCH * GDIM, g_ws);
            } else if (s >= NPAST) {
                matvec12<<<dim3(BATCH * 32), dim3(256), 0, stream>>>(
                    (const unsigned char*)d_ws, z_ws, scale_ws, g0_ws, g_ws);
            }
            if (s < NPAST - 1) {
                // past steps 0..8: decoder/state provably dead -> LSTM only
                lstmk<<<dim3(BATCH), dim3(512), 0, stream>>>(g_ws, z_ws, c_ws);
            } else {
                stepk<<<dim3(BATCH), dim3(512), 0, stream>>>(prv, pq, pro, pqo, pc, trp, tq,
                    se_w1, se_b1, se_w2, se_b2, oe_w1, oe_b1, oe_w2, oe_b2,
                    de_w1, de_b1, de_w2, de_b2, de_w3, de_b3,
                    outp, z_ws, g_ws, c_ws, car_ws, s, 0);
            }
        }
    } else {
        for (int s = 0; s < NSTEPS; ++s) {
            matvec_f32<<<dim3(BATCH * 32), dim3(256), 0, stream>>>(pw, z_ws, pb, g_ws);
            stepk<<<dim3(BATCH), dim3(512), 0, stream>>>(prv, pq, pro, pqo, pc, trp, tq,
                se_w1, se_b1, se_w2, se_b2, oe_w1, oe_b1, oe_w2, oe_b2,
                de_w1, de_b1, de_w2, de_b2, de_w3, de_b3,
                outp, z_ws, g_ws, c_ws, car_ws, s, 0);
        }
    }
}

// Round 15
// 3417.459 us; speedup vs baseline: 1.4657x; 1.1846x over previous
//
#include <hip/hip_runtime.h>
#include <hip/hip_bf16.h>
#include <math.h>

#define BATCH 128
#define QD 88
#define HDIM 512
#define ZDIM 1280
#define GDIM 2048
#define PROW 1024          // packed bytes per row (int8); quad stride = 4*PROW
#define QSTRIDE 4096
#define NPAST 10
#define NTRANS 29
#define NSTEPS (NPAST + NTRANS)
#define OUTD 95
#define POSE_ELEMS (BATCH * 30 * 91)

typedef float f32x4 __attribute__((ext_vector_type(4)));
typedef unsigned int u32x4 __attribute__((ext_vector_type(4)));

__device__ __forceinline__ float sig_(float x) { return 1.0f / (1.0f + expf(-x)); }
__device__ __forceinline__ void dot4_(const u32x4 wv, const float4 zv, float& d) {
    const float4 f = *(const float4*)&wv;
    d = fmaf(f.x, zv.x, d); d = fmaf(f.y, zv.y, d);
    d = fmaf(f.z, zv.z, d); d = fmaf(f.w, zv.w, d);
}
__device__ __forceinline__ void dot4u_(const uint4 wv, const float4 zv, float& d) {
    const float4 f = *(const float4*)&wv;
    d = fmaf(f.x, zv.x, d); d = fmaf(f.y, zv.y, d);
    d = fmaf(f.z, zv.z, d); d = fmaf(f.w, zv.w, d);
}
__device__ __forceinline__ void fma4_(float4& acc, float x, const float4 w) {
    acc.x = fmaf(x, w.x, acc.x); acc.y = fmaf(x, w.y, acc.y);
    acc.z = fmaf(x, w.z, acc.z); acc.w = fmaf(x, w.w, acc.w);
}
__device__ __forceinline__ unsigned q8_(float w, float inv) {
    const unsigned u = __float2uint_rn(fmaf(w, inv, 128.0f));
    return (u > 255u) ? 255u : u;
}
// pack 4 fp32 (bit patterns in u32x4) into one dword of biased int8
__device__ __forceinline__ unsigned pack8_(const u32x4 a, float inv) {
    return q8_(__uint_as_float(a.x), inv) | (q8_(__uint_as_float(a.y), inv) << 8)
         | (q8_(__uint_as_float(a.z), inv) << 16) | (q8_(__uint_as_float(a.w), inv) << 24);
}
// signed dot of a 4-weight int8 dword with a float4 z fragment (byte - 128)
__device__ __forceinline__ float d8_(unsigned d, const float4 z) {
    float acc = 0.f;
    acc = fmaf((float)((int)(d & 0xFFu) - 128), z.x, acc);
    acc = fmaf((float)((int)((d >> 8) & 0xFFu) - 128), z.y, acc);
    acc = fmaf((float)((int)((d >> 16) & 0xFFu) - 128), z.z, acc);
    acc = fmaf((float)((int)(d >> 24) - 128), z.w, acc);
    return acc;
}
__device__ __forceinline__ float wredmax_(float m) {
    #pragma unroll
    for (int s = 32; s >= 1; s >>= 1) m = fmaxf(m, __shfl_xor(m, s, 64));
    return m;
}
__device__ __forceinline__ float amax4_(const u32x4 a, float m) {
    m = fmaxf(m, fabsf(__uint_as_float(a.x))); m = fmaxf(m, fabsf(__uint_as_float(a.y)));
    m = fmaxf(m, fabsf(__uint_as_float(a.z))); m = fmaxf(m, fabsf(__uint_as_float(a.w)));
    return m;
}

// ---- step-0 GEMV over fp32 weights (NT), fused with int8 quantization + static fold ----
// Quad layout (4 rows, 4096 B): state [0,2048) = {rows01@0, rows23@1024}, h [2048,4096).
// Lane L uint4 at sub*1024 + L*16 = {r_even d0, r_even d1, r_odd d0, r_odd d1};
// dword d0 = cols {4L..4L+3}, d1 = cols {256+4L..256+4L+3} of the 512-col half.
__global__ void __launch_bounds__(256)
matvec0_conv(const float* __restrict__ W, const float* __restrict__ z_ws,
             const float* __restrict__ pred_bias, unsigned char* __restrict__ Wp,
             float* __restrict__ scale_ws, float* __restrict__ g_ws, float* __restrict__ g0_ws)
{
    const int b = blockIdx.x >> 5, chunk = blockIdx.x & 31;
    const int wave = threadIdx.x >> 6, lane = threadIdx.x & 63;
    const int row0 = chunk * 64 + wave * 16;
    const float* zb = z_ws + b * ZDIM;
    const float biasv = (lane < 16) ? pred_bias[b * GDIM + row0 + lane] : 0.f;
    const int l4 = lane * 4;
    const float4 z0 = *(const float4*)(zb + l4);
    const float4 z1 = *(const float4*)(zb + 256 + l4);
    const float4 zh = *(const float4*)(zb + 512 + l4);
    const float4 z3 = *(const float4*)(zb + 768 + l4);
    const float4 z4 = *(const float4*)(zb + 1024 + l4);
    const char* wb = (const char*)W + (size_t)b * GDIM * ZDIM * 4;
    char* dstB = (char*)Wp + (size_t)b * GDIM * PROW;

    #define ISSUE(p, B) { const char* a_ = wb + (size_t)(row0 + 2 * (p)) * (ZDIM * 4) + lane * 16; \
        _Pragma("unroll") for (int i = 0; i < 10; ++i) \
            B[i] = __builtin_nontemporal_load((const u32x4*)(a_ + i * 1024)); }

    u32x4 bufa[10], bufb[10];
    ISSUE(0, bufa);
    #pragma unroll
    for (int p = 0; p < 8; ++p) {
        u32x4* cur = (p & 1) ? bufb : bufa;
        u32x4* nxt = (p & 1) ? bufa : bufb;
        if (p < 7) ISSUE(p + 1, nxt);
        float dynA = 0.f, dynB = 0.f, statA = 0.f, statB = 0.f;
        dot4_(cur[0], z0, dynA); dot4_(cur[1], z1, dynA);
        dot4_(cur[2], zh, statA);
        dot4_(cur[3], z3, dynA); dot4_(cur[4], z4, dynA);
        dot4_(cur[5], z0, dynB); dot4_(cur[6], z1, dynB);
        dot4_(cur[7], zh, statB);
        dot4_(cur[8], z3, dynB); dot4_(cur[9], z4, dynB);
        float m0 = 0.f, m1 = 0.f;
        m0 = amax4_(cur[0], m0); m0 = amax4_(cur[1], m0);
        m0 = amax4_(cur[3], m0); m0 = amax4_(cur[4], m0);
        m1 = amax4_(cur[5], m1); m1 = amax4_(cur[6], m1);
        m1 = amax4_(cur[8], m1); m1 = amax4_(cur[9], m1);
        m0 = wredmax_(m0); m1 = wredmax_(m1);
        const float s0 = m0 * (1.f / 127.f), s1 = m1 * (1.f / 127.f);
        const float inv0 = (m0 > 0.f) ? 127.f / m0 : 0.f;
        const float inv1 = (m1 > 0.f) ? 127.f / m1 : 0.f;
        // rows 2p (scale inv0) and 2p+1 (inv1) form one complete subblock
        {
            const int rp = row0 + 2 * p;
            char* base = dstB + (size_t)(rp >> 2) * QSTRIDE + (size_t)((rp >> 1) & 1) * 1024
                       + lane * 16;
            u32x4 v;
            v.x = pack8_(cur[0], inv0); v.y = pack8_(cur[1], inv0);
            v.z = pack8_(cur[5], inv1); v.w = pack8_(cur[6], inv1);
            __builtin_nontemporal_store(v, (u32x4*)(base));
            v.x = pack8_(cur[3], inv0); v.y = pack8_(cur[4], inv0);
            v.z = pack8_(cur[8], inv1); v.w = pack8_(cur[9], inv1);
            __builtin_nontemporal_store(v, (u32x4*)(base + 2048));
        }
        if (lane == 0) { scale_ws[b * GDIM + row0 + 2 * p] = s0;
                         scale_ws[b * GDIM + row0 + 2 * p + 1] = s1; }
        float sd0 = dynA + __shfl_xor(dynA, 32);
        float sd1 = dynB + __shfl_xor(dynB, 32);
        float ud = (lane < 32) ? sd0 : sd1;
        float ss0 = statA + __shfl_xor(statA, 32);
        float ss1 = statB + __shfl_xor(statB, 32);
        float us = (lane < 32) ? ss0 : ss1;
        #pragma unroll
        for (int m = 16; m >= 1; m >>= 1) { ud += __shfl_xor(ud, m); us += __shfl_xor(us, m); }
        const float badd = __shfl(biasv, 2 * p + ((lane >= 32) ? 1 : 0), 64);
        if (lane == 0 || lane == 32) {
            const int r = row0 + 2 * p + ((lane >= 32) ? 1 : 0);
            g0_ws[b * GDIM + r] = us + badd;
            g_ws[b * GDIM + r]  = ud + us + badd;
        }
    }
    #undef ISSUE
}

// helper: reduce a row pair (rA,rB) across the wave, add base+scale, write 2 rows
__device__ __forceinline__ void redwrite_(float rA, float rB, int lane,
                                          float g0v, float scv, int idx0,
                                          float* __restrict__ dst, int drow0) {
    const float sA = rA + __shfl_xor(rA, 32);
    const float sB = rB + __shfl_xor(rB, 32);
    float u = (lane < 32) ? sA : sB;
    #pragma unroll
    for (int m = 16; m >= 1; m >>= 1) u += __shfl_xor(u, m);
    const int hilo = (lane >= 32) ? 1 : 0;
    const float badd = __shfl(g0v, idx0 + hilo, 64);
    const float srow = __shfl(scv, idx0 + hilo, 64);
    const float val = badd + srow * u;
    if (lane == 0)       dst[drow0] = val;
    else if (lane == 32) dst[drow0 + 1] = val;
}

// ---- E-pass: E[s][b][row] = g0 + s_row*(W_state . enc[s])  (state blocks only, NT) ----
__global__ void __launch_bounds__(256)
epass(const unsigned char* __restrict__ Wp, const float* __restrict__ enc9,
      const float* __restrict__ scale_ws, const float* __restrict__ g0_ws,
      float* __restrict__ E_ws)
{
    const int b = blockIdx.x >> 5, chunk = blockIdx.x & 31;
    const int wave = threadIdx.x >> 6, lane = threadIdx.x & 63;
    const int row0 = chunk * 64 + wave * 16;
    const int q0 = row0 >> 2;
    const int l4 = lane * 4;
    float4 eA[9], eB[9];
    #pragma unroll
    for (int s = 0; s < 9; ++s) {
        const float* eb = enc9 + ((size_t)s * BATCH + b) * 512;
        eA[s] = *(const float4*)(eb + l4);
        eB[s] = *(const float4*)(eb + 256 + l4);
    }
    const float g0v = (lane < 16) ? g0_ws[b * GDIM + row0 + lane] : 0.f;
    const float scv = (lane < 16) ? scale_ws[b * GDIM + row0 + lane] : 0.f;
    const char* wb = (const char*)Wp + (size_t)b * GDIM * PROW;

    #define ISSUE(qq, B) { const char* a_ = wb + (size_t)(q0 + (qq)) * QSTRIDE + lane * 16; \
        B[0] = __builtin_nontemporal_load((const u32x4*)(a_)); \
        B[1] = __builtin_nontemporal_load((const u32x4*)(a_ + 1024)); }

    u32x4 bufa[2], bufb[2];
    ISSUE(0, bufa);
    #pragma unroll
    for (int qq = 0; qq < 4; ++qq) {
        u32x4* cur = (qq & 1) ? bufb : bufa;
        u32x4* nxt = (qq & 1) ? bufa : bufb;
        if (qq < 3) ISSUE(qq + 1, nxt);
        #pragma unroll
        for (int s = 0; s < 9; ++s) {
            const float r0 = d8_(cur[0].x, eA[s]) + d8_(cur[0].y, eB[s]);
            const float r1 = d8_(cur[0].z, eA[s]) + d8_(cur[0].w, eB[s]);
            const float r2 = d8_(cur[1].x, eA[s]) + d8_(cur[1].y, eB[s]);
            const float r3 = d8_(cur[1].z, eA[s]) + d8_(cur[1].w, eB[s]);
            float* dst = E_ws + ((size_t)s * BATCH + b) * GDIM;
            redwrite_(r0, r1, lane, g0v, scv, 4 * qq,     dst, row0 + 4 * qq);
            redwrite_(r2, r3, lane, g0v, scv, 4 * qq + 2, dst, row0 + 4 * qq + 2);
        }
    }
    #undef ISSUE
}

// ---- past-step GEMV (s=1..9): gates = E[s] + s_row*(W_h . h)  (h blocks, L3-resident) ----
__global__ void __launch_bounds__(256)
matvecH(const unsigned char* __restrict__ Wp, const float* __restrict__ z_ws,
        const float* __restrict__ scale_ws, const float* __restrict__ Es,
        float* __restrict__ g_ws)
{
    const int b = blockIdx.x >> 5, chunk = blockIdx.x & 31;
    const int wave = threadIdx.x >> 6, lane = threadIdx.x & 63;
    const int row0 = chunk * 64 + wave * 16;
    const int q0 = row0 >> 2;
    const float* zb = z_ws + b * ZDIM;
    const int l4 = lane * 4;
    const float4 z3 = *(const float4*)(zb + 768 + l4);
    const float4 z4 = *(const float4*)(zb + 1024 + l4);
    const float Ev  = (lane < 16) ? Es[b * GDIM + row0 + lane] : 0.f;
    const float scv = (lane < 16) ? scale_ws[b * GDIM + row0 + lane] : 0.f;
    const char* wb = (const char*)Wp + (size_t)b * GDIM * PROW;

    #define ISSUE(qq, B) { const char* a_ = wb + (size_t)(q0 + (qq)) * QSTRIDE + 2048 + lane * 16; \
        B[0] = *(const u32x4*)(a_); \
        B[1] = *(const u32x4*)(a_ + 1024); }

    u32x4 buf0[2], buf1[2], buf2[2];
    ISSUE(0, buf0);
    ISSUE(1, buf1);
    #pragma unroll
    for (int qq = 0; qq < 4; ++qq) {
        u32x4* cur = (qq % 3 == 0) ? buf0 : (qq % 3 == 1) ? buf1 : buf2;
        u32x4* nxt = ((qq + 2) % 3 == 0) ? buf0 : ((qq + 2) % 3 == 1) ? buf1 : buf2;
        if (qq < 2) ISSUE(qq + 2, nxt);
        const float r0 = d8_(cur[0].x, z3) + d8_(cur[0].y, z4);
        const float r1 = d8_(cur[0].z, z3) + d8_(cur[0].w, z4);
        const float r2 = d8_(cur[1].x, z3) + d8_(cur[1].y, z4);
        const float r3 = d8_(cur[1].z, z3) + d8_(cur[1].w, z4);
        float* dst = g_ws + b * GDIM;
        redwrite_(r0, r1, lane, Ev, scv, 4 * qq,     dst, row0 + 4 * qq);
        redwrite_(r2, r3, lane, Ev, scv, 4 * qq + 2, dst, row0 + 4 * qq + 2);
    }
    #undef ISSUE
}

// ---- transition-step GEMV over int8 quad layout (NT loads: stream past L3) ----
__global__ void __launch_bounds__(256)
matvec8(const unsigned char* __restrict__ Wp, const float* __restrict__ z_ws,
        const float* __restrict__ scale_ws, const float* __restrict__ g0_ws,
        float* __restrict__ g_ws)
{
    const int b = blockIdx.x >> 5, chunk = blockIdx.x & 31;
    const int wave = threadIdx.x >> 6, lane = threadIdx.x & 63;
    const int row0 = chunk * 64 + wave * 16;
    const int q0 = row0 >> 2;
    const float* zb = z_ws + b * ZDIM;
    const int l4 = lane * 4;
    const float4 z0 = *(const float4*)(zb + l4);
    const float4 z1 = *(const float4*)(zb + 256 + l4);
    const float4 z3 = *(const float4*)(zb + 768 + l4);
    const float4 z4 = *(const float4*)(zb + 1024 + l4);
    const float g0v = (lane < 16) ? g0_ws[b * GDIM + row0 + lane] : 0.f;
    const float scv = (lane < 16) ? scale_ws[b * GDIM + row0 + lane] : 0.f;
    const char* wb = (const char*)Wp + (size_t)b * GDIM * PROW;

    #define ISSUE(qq, B) { const char* a_ = wb + (size_t)(q0 + (qq)) * QSTRIDE + lane * 16; \
        B[0] = __builtin_nontemporal_load((const u32x4*)(a_)); \
        B[1] = __builtin_nontemporal_load((const u32x4*)(a_ + 1024)); \
        B[2] = __builtin_nontemporal_load((const u32x4*)(a_ + 2048)); \
        B[3] = __builtin_nontemporal_load((const u32x4*)(a_ + 3072)); }

    u32x4 buf0[4], buf1[4], buf2[4];
    ISSUE(0, buf0);
    ISSUE(1, buf1);
    #pragma unroll
    for (int qq = 0; qq < 4; ++qq) {
        u32x4* cur = (qq % 3 == 0) ? buf0 : (qq % 3 == 1) ? buf1 : buf2;
        u32x4* nxt = ((qq + 2) % 3 == 0) ? buf0 : ((qq + 2) % 3 == 1) ? buf1 : buf2;
        if (qq < 2) ISSUE(qq + 2, nxt);
        const float r0 = d8_(cur[0].x, z0) + d8_(cur[0].y, z1)
                       + d8_(cur[2].x, z3) + d8_(cur[2].y, z4);
        const float r1 = d8_(cur[0].z, z0) + d8_(cur[0].w, z1)
                       + d8_(cur[2].z, z3) + d8_(cur[2].w, z4);
        const float r2 = d8_(cur[1].x, z0) + d8_(cur[1].y, z1)
                       + d8_(cur[3].x, z3) + d8_(cur[3].y, z4);
        const float r3 = d8_(cur[1].z, z0) + d8_(cur[1].w, z1)
                       + d8_(cur[3].z, z3) + d8_(cur[3].w, z4);
        float* dst = g_ws + b * GDIM;
        redwrite_(r0, r1, lane, g0v, scv, 4 * qq,     dst, row0 + 4 * qq);
        redwrite_(r2, r3, lane, g0v, scv, 4 * qq + 2, dst, row0 + 4 * qq + 2);
    }
    #undef ISSUE
}

// ---- LSTM-only step for past steps 0..8 (decoder provably dead there) ----
__global__ void __launch_bounds__(512)
lstmk(const float* __restrict__ g_ws, float* __restrict__ z_ws, float* __restrict__ c_ws)
{
    const int b = blockIdx.x, t = threadIdx.x;
    const float* g = g_ws + b * GDIM;
    const float ig = g[t], fg = g[512 + t], gg = g[1024 + t], og = g[1536 + t];
    const float c2 = sig_(fg) * c_ws[b * HDIM + t] + sig_(ig) * tanhf(gg);
    c_ws[b * HDIM + t] = c2;
    z_ws[b * ZDIM + 768 + t] = sig_(og) * tanhf(c2);
}

// ---------------- init: state=0, h_target, step-0 encoders, glob presum ----------------
__global__ void __launch_bounds__(512)
initk(const float* __restrict__ past_root_vel, const float* __restrict__ past_quats,
      const float* __restrict__ past_root_offset, const float* __restrict__ past_quat_offset,
      const float* __restrict__ past_contacts, const float* __restrict__ target_quats,
      const float* __restrict__ init_root_pos,
      const float* __restrict__ se_w1, const float* __restrict__ se_b1,
      const float* __restrict__ se_w2, const float* __restrict__ se_b2,
      const float* __restrict__ oe_w1, const float* __restrict__ oe_b1,
      const float* __restrict__ oe_w2, const float* __restrict__ oe_b2,
      const float* __restrict__ te_w1, const float* __restrict__ te_b1,
      const float* __restrict__ te_w2, const float* __restrict__ te_b2,
      float* __restrict__ z_ws, float* __restrict__ c_ws, float* __restrict__ car_ws)
{
    const int b = blockIdx.x, t = threadIdx.x;
    __shared__ float tq[QD], bufA[512], bufB[512], sv[95], ov[91];

    if (t < 192) {
        float v = 0.f;
        if (t < 3) {
            v = init_root_pos[b * 3 + t];
            for (int s = 0; s < NPAST - 1; ++s) v += past_root_vel[(b * NPAST + s) * 3 + t];
        }
        car_ws[b * 192 + t] = v;
    }
    c_ws[b * HDIM + t] = 0.f;
    z_ws[b * ZDIM + 768 + t] = 0.f;
    if (t < QD) tq[t] = target_quats[b * QD + t];
    if (t < 4)  sv[t] = past_contacts[b * NPAST * 4 + t];
    if (t < QD) { sv[4 + t] = past_quats[b * NPAST * QD + t];
                  ov[3 + t] = past_quat_offset[b * NPAST * QD + t]; }
    if (t < 3)  { sv[92 + t] = past_root_vel[b * NPAST * 3 + t];
                  ov[t]      = past_root_offset[b * NPAST * 3 + t]; }
    __syncthreads();
    {
        float a = te_b1[t];
        #pragma unroll 8
        for (int i = 0; i < QD; ++i) a = fmaf(tq[i], te_w1[i * 512 + t], a);
        bufA[t] = fmaxf(a, 0.f);
    }
    __syncthreads();
    if (t < 256) {
        float a = te_b2[t];
        #pragma unroll 8
        for (int i = 0; i < 512; ++i) a = fmaf(bufA[i], te_w2[i * 256 + t], a);
        z_ws[b * ZDIM + 512 + t] = fmaxf(a, 0.f);
    }
    __syncthreads();
    {
        float aS = se_b1[t], aO = oe_b1[t];
        #pragma unroll 8
        for (int i = 0; i < 91; ++i) { aS = fmaf(sv[i], se_w1[i * 512 + t], aS);
                                       aO = fmaf(ov[i], oe_w1[i * 512 + t], aO); }
        #pragma unroll
        for (int i = 91; i < 95; ++i) aS = fmaf(sv[i], se_w1[i * 512 + t], aS);
        bufA[t] = fmaxf(aS, 0.f);
        bufB[t] = fmaxf(aO, 0.f);
    }
    __syncthreads();
    if (t < 256) {
        float a = se_b2[t];
        #pragma unroll 8
        for (int i = 0; i < 512; ++i) a = fmaf(bufA[i], se_w2[i * 256 + t], a);
        z_ws[b * ZDIM + t] = fmaxf(a, 0.f);
    } else {
        const int j = t - 256;
        float a = oe_b2[j];
        #pragma unroll 8
        for (int i = 0; i < 512; ++i) a = fmaf(bufB[i], oe_w2[i * 256 + j], a);
        z_ws[b * ZDIM + 256 + j] = fmaxf(a, 0.f);
    }
}

// ---- batch-encode past steps 1..9 -> enc9[(s-1)*BATCH + b][512] ----
__global__ void __launch_bounds__(512)
enc_past(const float* __restrict__ past_root_vel, const float* __restrict__ past_quats,
         const float* __restrict__ past_root_offset, const float* __restrict__ past_quat_offset,
         const float* __restrict__ past_contacts,
         const float* __restrict__ se_w1, const float* __restrict__ se_b1,
         const float* __restrict__ se_w2, const float* __restrict__ se_b2,
         const float* __restrict__ oe_w1, const float* __restrict__ oe_b1,
         const float* __restrict__ oe_w2, const float* __restrict__ oe_b2,
         float* __restrict__ enc9)
{
    const int b = blockIdx.x, t = threadIdx.x;
    const int s = blockIdx.y + 1;
    __shared__ float bufA[512], bufB[512], sv[95], ov[91];

    if (t < 4)  sv[t] = past_contacts[(b * NPAST + s) * 4 + t];
    if (t < QD) { sv[4 + t] = past_quats[(b * NPAST + s) * QD + t];
                  ov[3 + t] = past_quat_offset[(b * NPAST + s) * QD + t]; }
    if (t < 3)  { sv[92 + t] = past_root_vel[(b * NPAST + s) * 3 + t];
                  ov[t]      = past_root_offset[(b * NPAST + s) * 3 + t]; }
    __syncthreads();
    {
        float aS = se_b1[t], aO = oe_b1[t];
        #pragma unroll 8
        for (int i = 0; i < 91; ++i) { aS = fmaf(sv[i], se_w1[i * 512 + t], aS);
                                       aO = fmaf(ov[i], oe_w1[i * 512 + t], aO); }
        #pragma unroll
        for (int i = 91; i < 95; ++i) aS = fmaf(sv[i], se_w1[i * 512 + t], aS);
        bufA[t] = fmaxf(aS, 0.f);
        bufB[t] = fmaxf(aO, 0.f);
    }
    __syncthreads();
    float* dst = enc9 + ((size_t)(s - 1) * BATCH + b) * 512;
    if (t < 256) {
        float a = se_b2[t];
        #pragma unroll 8
        for (int i = 0; i < 512; ++i) a = fmaf(bufA[i], se_w2[i * 256 + t], a);
        dst[t] = fmaxf(a, 0.f);
    } else {
        const int j = t - 256;
        float a = oe_b2[j];
        #pragma unroll 8
        for (int i = 0; i < 512; ++i) a = fmaf(bufB[i], oe_w2[i * 256 + j], a);
        dst[256 + j] = fmaxf(a, 0.f);
    }
}

// ---------------- per-step: LSTM + decoder + state update + next encoders ----------------
__global__ void __launch_bounds__(512)
stepk(const float* __restrict__ past_root_vel, const float* __restrict__ past_quats,
      const float* __restrict__ past_root_offset, const float* __restrict__ past_quat_offset,
      const float* __restrict__ past_contacts, const float* __restrict__ target_root_pos,
      const float* __restrict__ target_quats,
      const float* __restrict__ se_w1, const float* __restrict__ se_b1,
      const float* __restrict__ se_w2, const float* __restrict__ se_b2,
      const float* __restrict__ oe_w1, const float* __restrict__ oe_b1,
      const float* __restrict__ oe_w2, const float* __restrict__ oe_b2,
      const float* __restrict__ de_w1, const float* __restrict__ de_b1,
      const float* __restrict__ de_w2, const float* __restrict__ de_b2,
      const float* __restrict__ de_w3, const float* __restrict__ de_b3,
      float* __restrict__ out, float* __restrict__ z_ws, const float* __restrict__ g_ws,
      float* __restrict__ c_ws, float* __restrict__ car_ws, int s, int skip_enc)
{
    const int b = blockIdx.x, t = threadIdx.x;
    __shared__ float4 part4[512];
    __shared__ __align__(16) float h2s[HDIM], bufA[512], bufB[512], d2[256];
    __shared__ float outv[OUTD], nq[QD], sv[95], ov[91], carryL[192], tq[QD], trp[3];
    __shared__ float rvn[3], globn[3], contn[4];

    if (t < 192) carryL[t] = car_ws[b * 192 + t];
    if (t < QD) tq[t] = target_quats[b * QD + t];
    if (t < 3)  trp[t] = target_root_pos[b * 3 + t];

    {
        const float* g = g_ws + b * GDIM;
        const float ig = g[t], fg = g[512 + t], gg = g[1024 + t], og = g[1536 + t];
        const float c2 = sig_(fg) * c_ws[b * HDIM + t] + sig_(ig) * tanhf(gg);
        c_ws[b * HDIM + t] = c2;
        const float h2 = sig_(og) * tanhf(c2);
        h2s[t] = h2;
        z_ws[b * ZDIM + 768 + t] = h2;
    }
    __syncthreads();
    {
        const int c = t & 127, s4 = t >> 7;
        float4 acc = {0.f, 0.f, 0.f, 0.f};
        const float* w = de_w1 + (size_t)(s4 * 128) * 512 + 4 * c;
        #pragma unroll 8
        for (int k = 0; k < 128; ++k)
            fma4_(acc, h2s[s4 * 128 + k], *(const float4*)(w + (size_t)k * 512));
        part4[t] = acc;
    }
    __syncthreads();
    if (t < 128) {
        float4 v = part4[t];
        #pragma unroll
        for (int s4 = 1; s4 < 4; ++s4) { const float4 p = part4[s4 * 128 + t];
            v.x += p.x; v.y += p.y; v.z += p.z; v.w += p.w; }
        const float4 bb = *(const float4*)(de_b1 + 4 * t);
        float4 r; r.x = fmaxf(v.x + bb.x, 0.f); r.y = fmaxf(v.y + bb.y, 0.f);
        r.z = fmaxf(v.z + bb.z, 0.f); r.w = fmaxf(v.w + bb.w, 0.f);
        *(float4*)&bufA[4 * t] = r;
    }
    __syncthreads();
    {
        const int c = t & 63, s8 = t >> 6;
        float4 acc = {0.f, 0.f, 0.f, 0.f};
        const float* w = de_w2 + (size_t)(s8 * 64) * 256 + 4 * c;
        #pragma unroll 8
        for (int k = 0; k < 64; ++k)
            fma4_(acc, bufA[s8 * 64 + k], *(const float4*)(w + (size_t)k * 256));
        part4[t] = acc;
    }
    __syncthreads();
    if (t < 64) {
        float4 v = part4[t];
        #pragma unroll
        for (int s8 = 1; s8 < 8; ++s8) { const float4 p = part4[s8 * 64 + t];
            v.x += p.x; v.y += p.y; v.z += p.z; v.w += p.w; }
        const float4 bb = *(const float4*)(de_b2 + 4 * t);
        float4 r; r.x = fmaxf(v.x + bb.x, 0.f); r.y = fmaxf(v.y + bb.y, 0.f);
        r.z = fmaxf(v.z + bb.z, 0.f); r.w = fmaxf(v.w + bb.w, 0.f);
        *(float4*)&d2[4 * t] = r;
    }
    __syncthreads();
    if (t < OUTD) {
        float acc = de_b3[t];
        #pragma unroll 16
        for (int i = 0; i < 256; ++i) acc = fmaf(d2[i], de_w3[i * OUTD + t], acc);
        outv[t] = acc;
    }
    __syncthreads();

    const bool pastS = (s < NPAST);
    if (t < QD) {
        const float qin = pastS ? past_quats[(b * NPAST + s) * QD + t] : carryL[10 + t];
        nq[t] = outv[t] + qin;
    }
    __syncthreads();
    if (t < 22) {
        const float a = nq[4 * t], b2 = nq[4 * t + 1], c3 = nq[4 * t + 2], d4 = nq[4 * t + 3];
        const float inv = 1.f / fmaxf(sqrtf(a * a + b2 * b2 + c3 * c3 + d4 * d4), 1e-12f);
        nq[4 * t] = a * inv; nq[4 * t + 1] = b2 * inv; nq[4 * t + 2] = c3 * inv; nq[4 * t + 3] = d4 * inv;
    }
    if (t < 3) {
        const float rin = pastS ? past_root_vel[(b * NPAST + s) * 3 + t] : carryL[3 + t];
        const float nrv = outv[88 + t] + rin;
        const float g = carryL[t] + (pastS ? rin : nrv);
        rvn[t] = nrv; globn[t] = g;
    }
    if (t < 4) contn[t] = sig_(outv[91 + t]);
    __syncthreads();

    if (t < 3) { car_ws[b * 192 + t] = globn[t]; car_ws[b * 192 + 3 + t] = rvn[t];
                 car_ws[b * 192 + 186 + t] = globn[t] - trp[t]; }
    if (t < 4) car_ws[b * 192 + 6 + t] = contn[t];
    if (t < QD) { car_ws[b * 192 + 10 + t] = nq[t]; car_ws[b * 192 + 98 + t] = nq[t] - tq[t]; }
    if (s == NPAST - 1) {
        const size_t pb = (size_t)b * 30 * 91;
        if (t < 3)  out[pb + t] = rvn[t];
        if (t < QD) out[pb + 3 + t] = nq[t];
        if (t < 4)  out[POSE_ELEMS + (size_t)b * 30 * 4 + t] = contn[t];
    } else if (!pastS) {
        const int k = s - NPAST + 1;
        const size_t pb = ((size_t)b * 30 + k) * 91;
        if (t < 3)  out[pb + t] = globn[t];
        if (t < QD) out[pb + 3 + t] = nq[t];
        if (t < 4)  out[POSE_ELEMS + ((size_t)b * 30 + k) * 4 + t] = contn[t];
    }
    if (s == NSTEPS - 1) return;
    if (skip_enc) return;

    const int nx = s + 1;
    if (nx < NPAST) {
        if (t < 4)  sv[t] = past_contacts[(b * NPAST + nx) * 4 + t];
        if (t < QD) { sv[4 + t] = past_quats[(b * NPAST + nx) * QD + t];
                      ov[3 + t] = past_quat_offset[(b * NPAST + nx) * QD + t]; }
        if (t < 3)  { sv[92 + t] = past_root_vel[(b * NPAST + nx) * 3 + t];
                      ov[t]      = past_root_offset[(b * NPAST + nx) * 3 + t]; }
    } else {
        if (t < 4)  sv[t] = contn[t];
        if (t < QD) { sv[4 + t] = nq[t]; ov[3 + t] = nq[t] - tq[t]; }
        if (t < 3)  { sv[92 + t] = rvn[t]; ov[t] = globn[t] - trp[t]; }
    }
    __syncthreads();
    {
        const int tt = t & 255, enc = t >> 8;
        const int c = tt & 127, sl = tt >> 7;
        const float* inp = enc ? ov : sv;
        const float* w1  = enc ? oe_w1 : se_w1;
        const int nin  = enc ? 91 : 95;
        const int half = enc ? 46 : 48;
        const int i0 = sl * half;
        const int iend = (i0 + half < nin) ? (i0 + half) : nin;
        float4 acc = {0.f, 0.f, 0.f, 0.f};
        #pragma unroll 8
        for (int k = 0; k < 48; ++k) {
            const int i = i0 + k;
            if (i < iend) fma4_(acc, inp[i], *(const float4*)(w1 + (size_t)i * 512 + 4 * c));
        }
        part4[enc * 256 + tt] = acc;
    }
    __syncthreads();
    if (t < 128) {
        const float4 a = part4[t], b2 = part4[128 + t];
        const float4 bb = *(const float4*)(se_b1 + 4 * t);
        float4 r; r.x = fmaxf(a.x + b2.x + bb.x, 0.f); r.y = fmaxf(a.y + b2.y + bb.y, 0.f);
        r.z = fmaxf(a.z + b2.z + bb.z, 0.f); r.w = fmaxf(a.w + b2.w + bb.w, 0.f);
        *(float4*)&bufA[4 * t] = r;
    } else if (t < 256) {
        const int c = t - 128;
        const float4 a = part4[256 + c], b2 = part4[384 + c];
        const float4 bb = *(const float4*)(oe_b1 + 4 * c);
        float4 r; r.x = fmaxf(a.x + b2.x + bb.x, 0.f); r.y = fmaxf(a.y + b2.y + bb.y, 0.f);
        r.z = fmaxf(a.z + b2.z + bb.z, 0.f); r.w = fmaxf(a.w + b2.w + bb.w, 0.f);
        *(float4*)&bufB[4 * c] = r;
    }
    __syncthreads();
    {
        const int tt = t & 255, enc = t >> 8;
        const int c = tt & 63, sl = tt >> 6;
        const float* inp = enc ? bufB : bufA;
        const float* w2  = enc ? oe_w2 : se_w2;
        float4 acc = {0.f, 0.f, 0.f, 0.f};
        const float* w = w2 + (size_t)(sl * 128) * 256 + 4 * c;
        #pragma unroll 8
        for (int k = 0; k < 128; ++k)
            fma4_(acc, inp[sl * 128 + k], *(const float4*)(w + (size_t)k * 256));
        part4[enc * 256 + tt] = acc;
    }
    __syncthreads();
    if (t < 64) {
        float4 v = part4[t];
        #pragma unroll
        for (int sl = 1; sl < 4; ++sl) { const float4 p = part4[sl * 64 + t];
            v.x += p.x; v.y += p.y; v.z += p.z; v.w += p.w; }
        const float4 bb = *(const float4*)(se_b2 + 4 * t);
        float4 r; r.x = fmaxf(v.x + bb.x, 0.f); r.y = fmaxf(v.y + bb.y, 0.f);
        r.z = fmaxf(v.z + bb.z, 0.f); r.w = fmaxf(v.w + bb.w, 0.f);
        *(float4*)(z_ws + b * ZDIM + 4 * t) = r;
    } else if (t < 128) {
        const int c = t - 64;
        float4 v = part4[256 + c];
        #pragma unroll
        for (int sl = 1; sl < 4; ++sl) { const float4 p = part4[256 + sl * 64 + c];
            v.x += p.x; v.y += p.y; v.z += p.z; v.w += p.w; }
        const float4 bb = *(const float4*)(oe_b2 + 4 * c);
        float4 r; r.x = fmaxf(v.x + bb.x, 0.f); r.y = fmaxf(v.y + bb.y, 0.f);
        r.z = fmaxf(v.z + bb.z, 0.f); r.w = fmaxf(v.w + bb.w, 0.f);
        *(float4*)(z_ws + b * ZDIM + 256 + 4 * c) = r;
    }
}

// ================= fp32 fallback path (ws too small) =================
__global__ void __launch_bounds__(256)
matvec_f32(const float* __restrict__ W, const float* __restrict__ z_ws,
           const float* __restrict__ pred_bias, float* __restrict__ g_ws)
{
    const int b = blockIdx.x >> 5, chunk = blockIdx.x & 31;
    const int wave = threadIdx.x >> 6, lane = threadIdx.x & 63;
    const int row0 = chunk * 64 + wave * 16;
    const float* zb = z_ws + b * ZDIM;
    const float biasv = (lane < 16) ? pred_bias[b * GDIM + row0 + lane] : 0.f;
    const int l4 = lane * 4;
    const float4 z0 = *(const float4*)(zb + l4);
    const float4 z1 = *(const float4*)(zb + 256 + l4);
    const float4 z2 = *(const float4*)(zb + 512 + l4);
    const float4 z3 = *(const float4*)(zb + 768 + l4);
    const float4 z4 = *(const float4*)(zb + 1024 + l4);
    const char* wb = (const char*)W + (size_t)b * GDIM * ZDIM * 4;

    #define ISSUE(p, B) { const char* a_ = wb + (size_t)(row0 + 2 * (p)) * (ZDIM * 4) + lane * 16; \
        _Pragma("unroll") for (int i = 0; i < 10; ++i) B[i] = *(const uint4*)(a_ + i * 1024); }

    uint4 bufa[10], bufb[10];
    ISSUE(0, bufa);
    #pragma unroll
    for (int p = 0; p < 8; ++p) {
        uint4* cur = (p & 1) ? bufb : bufa;
        uint4* nxt = (p & 1) ? bufa : bufb;
        if (p < 7) ISSUE(p + 1, nxt);
        float accA = 0.f, accB = 0.f;
        dot4u_(cur[0], z0, accA); dot4u_(cur[1], z1, accA); dot4u_(cur[2], z2, accA);
        dot4u_(cur[3], z3, accA); dot4u_(cur[4], z4, accA);
        dot4u_(cur[5], z0, accB); dot4u_(cur[6], z1, accB); dot4u_(cur[7], z2, accB);
        dot4u_(cur[8], z3, accB); dot4u_(cur[9], z4, accB);
        float s0 = accA + __shfl_xor(accA, 32);
        float s1 = accB + __shfl_xor(accB, 32);
        float u = (lane < 32) ? s0 : s1;
        #pragma unroll
        for (int m = 16; m >= 1; m >>= 1) u += __shfl_xor(u, m);
        const float badd = __shfl(biasv, 2 * p + ((lane >= 32) ? 1 : 0), 64);
        if (lane == 0)       g_ws[b * GDIM + row0 + 2 * p]     = u + badd;
        else if (lane == 32) g_ws[b * GDIM + row0 + 2 * p + 1] = u + badd;
    }
    #undef ISSUE
}

extern "C" void kernel_launch(void* const* d_in, const int* in_sizes, int n_in,
                              void* d_out, int out_size, void* d_ws, size_t ws_size,
                              hipStream_t stream) {
    const float* prv = (const float*)d_in[0];
    const float* pq  = (const float*)d_in[1];
    const float* pro = (const float*)d_in[2];
    const float* pqo = (const float*)d_in[3];
    const float* pc  = (const float*)d_in[4];
    const float* trp = (const float*)d_in[5];
    const float* tq  = (const float*)d_in[6];
    const float* irp = (const float*)d_in[7];
    const float* pw  = (const float*)d_in[8];
    const float* pb  = (const float*)d_in[9];
    const float* se_w1 = (const float*)d_in[10]; const float* se_b1 = (const float*)d_in[11];
    const float* se_w2 = (const float*)d_in[12]; const float* se_b2 = (const float*)d_in[13];
    const float* oe_w1 = (const float*)d_in[14]; const float* oe_b1 = (const float*)d_in[15];
    const float* oe_w2 = (const float*)d_in[16]; const float* oe_b2 = (const float*)d_in[17];
    const float* te_w1 = (const float*)d_in[18]; const float* te_b1 = (const float*)d_in[19];
    const float* te_w2 = (const float*)d_in[20]; const float* te_b2 = (const float*)d_in[21];
    const float* de_w1 = (const float*)d_in[22]; const float* de_b1 = (const float*)d_in[23];
    const float* de_w2 = (const float*)d_in[24]; const float* de_b2 = (const float*)d_in[25];
    const float* de_w3 = (const float*)d_in[26]; const float* de_b3 = (const float*)d_in[27];
    float* outp = (float*)d_out;

    const size_t WPACKB = (size_t)BATCH * GDIM * PROW;     // 268.4 MB packed int8
    const size_t AUXB = (size_t)BATCH * (GDIM * 3 + ZDIM + HDIM + 192) * 4
                      + (size_t)9 * BATCH * 512 * 4
                      + (size_t)9 * BATCH * GDIM * 4;
    const bool bf = ws_size >= WPACKB + AUXB;

    char* base = (char*)d_ws;
    float* scale_ws; float* g0_ws; float* z_ws;
    if (bf) {
        scale_ws = (float*)(base + WPACKB);
        g0_ws    = scale_ws + (size_t)BATCH * GDIM;
        z_ws     = g0_ws + (size_t)BATCH * GDIM;
    } else {
        scale_ws = nullptr;
        g0_ws    = nullptr;
        z_ws     = (float*)base;
    }
    float* g_ws    = z_ws + (size_t)BATCH * ZDIM;
    float* c_ws    = g_ws + (size_t)BATCH * GDIM;
    float* car_ws  = c_ws + (size_t)BATCH * HDIM;
    float* enc9_ws = car_ws + (size_t)BATCH * 192;
    float* E_ws    = enc9_ws + (size_t)9 * BATCH * 512;

    initk<<<dim3(BATCH), dim3(512), 0, stream>>>(prv, pq, pro, pqo, pc, tq, irp,
        se_w1, se_b1, se_w2, se_b2, oe_w1, oe_b1, oe_w2, oe_b2,
        te_w1, te_b1, te_w2, te_b2, z_ws, c_ws, car_ws);

    if (bf) {
        enc_past<<<dim3(BATCH, 9), dim3(512), 0, stream>>>(prv, pq, pro, pqo, pc,
            se_w1, se_b1, se_w2, se_b2, oe_w1, oe_b1, oe_w2, oe_b2, enc9_ws);
        matvec0_conv<<<dim3(BATCH * 32), dim3(256), 0, stream>>>(
            pw, z_ws, pb, (unsigned char*)d_ws, scale_ws, g_ws, g0_ws);
        epass<<<dim3(BATCH * 32), dim3(256), 0, stream>>>(
            (const unsigned char*)d_ws, enc9_ws, scale_ws, g0_ws, E_ws);
        for (int s = 0; s < NSTEPS; ++s) {
            if (s >= 1 && s < NPAST) {
                matvecH<<<dim3(BATCH * 32), dim3(256), 0, stream>>>(
                    (const unsigned char*)d_ws, z_ws, scale_ws,
                    E_ws + (size_t)(s - 1) * BATCH * GDIM, g_ws);
            } else if (s >= NPAST) {
                matvec8<<<dim3(BATCH * 32), dim3(256), 0, stream>>>(
                    (const unsigned char*)d_ws, z_ws, scale_ws, g0_ws, g_ws);
            }
            if (s < NPAST - 1) {
                lstmk<<<dim3(BATCH), dim3(512), 0, stream>>>(g_ws, z_ws, c_ws);
            } else {
                stepk<<<dim3(BATCH), dim3(512), 0, stream>>>(prv, pq, pro, pqo, pc, trp, tq,
                    se_w1, se_b1, se_w2, se_b2, oe_w1, oe_b1, oe_w2, oe_b2,
                    de_w1, de_b1, de_w2, de_b2, de_w3, de_b3,
                    outp, z_ws, g_ws, c_ws, car_ws, s, 0);
            }
        }
    } else {
        for (int s = 0; s < NSTEPS; ++s) {
            matvec_f32<<<dim3(BATCH * 32), dim3(256), 0, stream>>>(pw, z_ws, pb, g_ws);
            stepk<<<dim3(BATCH), dim3(512), 0, stream>>>(prv, pq, pro, pqo, pc, trp, tq,
                se_w1, se_b1, se_w2, se_b2, oe_w1, oe_b1, oe_w2, oe_b2,
                de_w1, de_b1, de_w2, de_b2, de_w3, de_b3,
                outp, z_ws, g_ws, c_ws, car_ws, s, 0);
        }
    }
}